// Round 1
// baseline (538.087 us; speedup 1.0000x reference)
//
#include <hip/hip_runtime.h>
#include <cstdint>
#include <cstddef>

// BinSAGE: 2-layer GraphSAGE with sign-binarized weights.
// N=50000 nodes, E=800000 edges, dims 96 -> 128 -> 64.
// Plan:
//   CSR build (count/scan/fill) -> agg1 (mean of x over in-edges, 96 wide)
//   gemm1: [AGG1 | x] (K=192) @ S1 -> relu -> H [N,128]
//   gemm2: H @ S2 (K=128) -> [T2 | R2]  (T2 = h@sgn(w2l)^T, R2 = h@sgn(w2r)^T + b2)
//   final: out = inv_deg * segsum(T2[src]) + R2     (aggregate AFTER transform: 64 wide)

#define N_NODES 50000
#define IN_DIM 96
#define HID 128
#define OUT_DIM 64
#define KC 16

static inline size_t alignUp(size_t v, size_t a) { return (v + a - 1) & ~(a - 1); }

__global__ void count_deg_kernel(const int* __restrict__ dst, int* __restrict__ deg, int E) {
  int e = blockIdx.x * blockDim.x + threadIdx.x;
  if (e < E) atomicAdd(&deg[dst[e]], 1);
}

__global__ __launch_bounds__(1024) void scan_kernel(const int* __restrict__ deg,
    int* __restrict__ rowptr, int* __restrict__ cursor, float* __restrict__ inv_deg,
    int n, int chunk) {
  __shared__ int smem[1024];
  const int t = threadIdx.x;
  const int begI = t * chunk;
  const int endI = min(begI + chunk, n);
  int s = 0;
  for (int i = begI; i < endI; ++i) s += deg[i];
  smem[t] = s;
  __syncthreads();
  for (int off = 1; off < 1024; off <<= 1) {
    int v = (t >= off) ? smem[t - off] : 0;
    __syncthreads();
    smem[t] += v;
    __syncthreads();
  }
  int run = smem[t] - s;  // exclusive prefix of this thread's chunk
  for (int i = begI; i < endI; ++i) {
    int d = deg[i];
    rowptr[i] = run;
    cursor[i] = run;
    inv_deg[i] = 1.0f / (float)(d > 1 ? d : 1);
    run += d;
  }
  if (t == 1023) rowptr[n] = smem[1023];
}

__global__ void build_adj_kernel(const int* __restrict__ src, const int* __restrict__ dst,
    int* __restrict__ cursor, int* __restrict__ adj, int E) {
  int e = blockIdx.x * blockDim.x + threadIdx.x;
  if (e < E) {
    int slot = atomicAdd(&cursor[dst[e]], 1);
    adj[slot] = src[e];
  }
}

__device__ __forceinline__ float sgnf(float w) {
  return (w > 0.f) ? 1.f : ((w < 0.f) ? -1.f : 0.f);
}

// S1: [192][128] K-major: k<96 -> sgn(w1l[j][k]); k>=96 -> sgn(w1r[j][k-96])
// S2: [128][128] K-major: j<64 -> sgn(w2l[j][k]);  j>=64 -> sgn(w2r[j-64][k])
__global__ void prep_s_kernel(const float* __restrict__ w1l, const float* __restrict__ w1r,
                              const float* __restrict__ w2l, const float* __restrict__ w2r,
                              float* __restrict__ S1, float* __restrict__ S2) {
  int idx = blockIdx.x * blockDim.x + threadIdx.x;
  if (idx < 192 * 128) {
    int k = idx >> 7, j = idx & 127;
    float w = (k < 96) ? w1l[j * 96 + k] : w1r[j * 96 + (k - 96)];
    S1[idx] = sgnf(w);
  } else if (idx < 192 * 128 + 128 * 128) {
    int i2 = idx - 192 * 128;
    int k = i2 >> 7, j = i2 & 127;
    float w = (j < 64) ? w2l[j * 128 + k] : w2r[(j - 64) * 128 + k];
    S2[i2] = sgnf(w);
  }
}

// One wave per node: lane f accumulates x[src][f]; 96 = 64 + 32 features.
__global__ __launch_bounds__(256) void agg1_kernel(const float* __restrict__ x,
    const int* __restrict__ adj, const int* __restrict__ rowptr,
    const float* __restrict__ inv_deg, float* __restrict__ AGG, int nNodes) {
  const int wave = threadIdx.x >> 6;
  const int lane = threadIdx.x & 63;
  const int n = blockIdx.x * 4 + wave;
  if (n >= nNodes) return;
  const int beg = rowptr[n], end = rowptr[n + 1];
  float a0 = 0.f, a1 = 0.f;
  for (int e = beg; e < end; ++e) {
    const int s = adj[e];
    const float* xr = x + (size_t)s * IN_DIM;
    a0 += xr[lane];
    if (lane < 32) a1 += xr[64 + lane];
  }
  const float inv = inv_deg[n];
  AGG[(size_t)n * IN_DIM + lane] = a0 * inv;
  if (lane < 32) AGG[(size_t)n * IN_DIM + 64 + lane] = a1 * inv;
}

// Tiled f32 GEMM: C[M][128] = A[M][K] * B[K][128]  (B is K-major, n-contiguous)
// A element (row,k): k<split -> Aa[row*lda + k]; else Ab[row*lda + (k-split)]
// mode 0: C = relu(C + bias[col])          (gemm1, bias=b1[128])
// mode 1: col>=64 -> C += bias[col-64]     (gemm2, bias=b2[64])
__global__ __launch_bounds__(256) void gemm_kernel(
    const float* __restrict__ Aa, const float* __restrict__ Ab, int lda, int split, int K,
    const float* __restrict__ B, const float* __restrict__ bias,
    float* __restrict__ C, int ldc, int M, int mode) {
  __shared__ float As[KC][68];
  __shared__ float Bs[KC][132];
  const int tid = threadIdx.x;
  const int tx = tid & 15;   // col group: cols tx*8 .. +7
  const int ty = tid >> 4;   // row group: rows ty*4 .. +3
  const int rowBase = blockIdx.x * 64;

  float acc[4][8];
#pragma unroll
  for (int i = 0; i < 4; ++i)
#pragma unroll
    for (int j = 0; j < 8; ++j) acc[i][j] = 0.f;

  // A staging: thread loads float4 along k for one row
  const int lm = tid >> 2;          // 0..63 row in tile
  const int lk = (tid & 3) * 4;     // 0,4,8,12
  const int arow = rowBase + lm;
  const bool aval = arow < M;
  // B staging: thread loads 8 consecutive floats of the [16][128] tile
  const int bk = tid >> 4;          // 0..15
  const int bn = (tid & 15) * 8;    // 0..120

  for (int k0 = 0; k0 < K; k0 += KC) {
    const int kk = k0 + lk;
    float4 av = make_float4(0.f, 0.f, 0.f, 0.f);
    if (aval) {
      const float* Arow = (kk < split) ? (Aa + (size_t)arow * lda + kk)
                                       : (Ab + (size_t)arow * lda + (kk - split));
      av = *(const float4*)Arow;
    }
    const float4 bv0 = *(const float4*)(B + (size_t)(k0 + bk) * 128 + bn);
    const float4 bv1 = *(const float4*)(B + (size_t)(k0 + bk) * 128 + bn + 4);
    __syncthreads();
    As[lk + 0][lm] = av.x;
    As[lk + 1][lm] = av.y;
    As[lk + 2][lm] = av.z;
    As[lk + 3][lm] = av.w;
    *(float4*)&Bs[bk][bn] = bv0;
    *(float4*)&Bs[bk][bn + 4] = bv1;
    __syncthreads();
#pragma unroll
    for (int k = 0; k < KC; ++k) {
      const float4 a4 = *(const float4*)&As[k][ty * 4];
      const float4 b4a = *(const float4*)&Bs[k][tx * 8];
      const float4 b4b = *(const float4*)&Bs[k][tx * 8 + 4];
      const float aa[4] = {a4.x, a4.y, a4.z, a4.w};
      const float bb[8] = {b4a.x, b4a.y, b4a.z, b4a.w, b4b.x, b4b.y, b4b.z, b4b.w};
#pragma unroll
      for (int i = 0; i < 4; ++i)
#pragma unroll
        for (int j = 0; j < 8; ++j) acc[i][j] = fmaf(aa[i], bb[j], acc[i][j]);
    }
  }

#pragma unroll
  for (int i = 0; i < 4; ++i) {
    const int r = rowBase + ty * 4 + i;
    if (r < M) {
      float o[8];
#pragma unroll
      for (int j = 0; j < 8; ++j) {
        float c = acc[i][j];
        const int col = tx * 8 + j;
        if (mode == 0) {
          c += bias[col];
          c = fmaxf(c, 0.f);
        } else {
          if (col >= 64) c += bias[col - 64];
        }
        o[j] = c;
      }
      float* Crow = C + (size_t)r * ldc + tx * 8;
      *(float4*)Crow = make_float4(o[0], o[1], o[2], o[3]);
      *(float4*)(Crow + 4) = make_float4(o[4], o[5], o[6], o[7]);
    }
  }
}

// out[n][c] = inv_deg[n] * sum_{e in CSR(n)} T2[src_e][c] + R2[n][c],  c<64
// TR layout: [N][128], cols 0..63 = T2, 64..127 = R2.
__global__ __launch_bounds__(256) void final_kernel(const float* __restrict__ TR,
    const int* __restrict__ adj, const int* __restrict__ rowptr,
    const float* __restrict__ inv_deg, float* __restrict__ out, int nNodes) {
  const int wave = threadIdx.x >> 6;
  const int lane = threadIdx.x & 63;
  const int n = blockIdx.x * 4 + wave;
  if (n >= nNodes) return;
  const int beg = rowptr[n], end = rowptr[n + 1];
  float acc = 0.f;
  for (int e = beg; e < end; ++e) {
    const int s = adj[e];
    acc += TR[(size_t)s * 128 + lane];
  }
  out[(size_t)n * 64 + lane] = acc * inv_deg[n] + TR[(size_t)n * 128 + 64 + lane];
}

extern "C" void kernel_launch(void* const* d_in, const int* in_sizes, int n_in,
                              void* d_out, int out_size, void* d_ws, size_t ws_size,
                              hipStream_t stream) {
  const float* x   = (const float*)d_in[0];
  const int*   ei  = (const int*)d_in[1];
  const float* w1l = (const float*)d_in[2];
  const float* b1  = (const float*)d_in[3];
  const float* w1r = (const float*)d_in[4];
  const float* w2l = (const float*)d_in[5];
  const float* b2  = (const float*)d_in[6];
  const float* w2r = (const float*)d_in[7];
  float* out = (float*)d_out;

  const int N = in_sizes[0] / IN_DIM;   // 50000
  const int E = in_sizes[1] / 2;        // 800000
  const int* src = ei;
  const int* dst = ei + E;

  // ---- workspace carve (all 256B aligned) ----
  char* p = (char*)d_ws;
  // region A: AGG1 [N][96] f32, later reused as TR [N][128] f32 -> max size
  float* AGG = (float*)p;
  float* TR  = (float*)p;
  p += alignUp((size_t)N * 128 * sizeof(float), 256);
  float* H = (float*)p;  p += alignUp((size_t)N * HID * sizeof(float), 256);
  float* S1 = (float*)p; p += alignUp(192 * 128 * sizeof(float), 256);
  float* S2 = (float*)p; p += alignUp(128 * 128 * sizeof(float), 256);
  int* deg = (int*)p;    p += alignUp((size_t)N * sizeof(int), 256);
  int* rowptr = (int*)p; p += alignUp((size_t)(N + 1) * sizeof(int), 256);
  int* cursor = (int*)p; p += alignUp((size_t)N * sizeof(int), 256);
  float* inv_deg = (float*)p; p += alignUp((size_t)N * sizeof(float), 256);
  int* adj = (int*)p;    p += alignUp((size_t)E * sizeof(int), 256);
  (void)ws_size; (void)n_in; (void)out_size;

  hipMemsetAsync(deg, 0, (size_t)N * sizeof(int), stream);

  const int eBlocks = (E + 255) / 256;
  count_deg_kernel<<<eBlocks, 256, 0, stream>>>(dst, deg, E);

  const int chunk = (N + 1023) / 1024;
  scan_kernel<<<1, 1024, 0, stream>>>(deg, rowptr, cursor, inv_deg, N, chunk);

  build_adj_kernel<<<eBlocks, 256, 0, stream>>>(src, dst, cursor, adj, E);

  prep_s_kernel<<<(192 * 128 + 128 * 128 + 255) / 256, 256, 0, stream>>>(w1l, w1r, w2l, w2r, S1, S2);

  const int nodeBlocks = (N + 3) / 4;
  agg1_kernel<<<nodeBlocks, 256, 0, stream>>>(x, adj, rowptr, inv_deg, AGG, N);

  const int gemmBlocks = (N + 63) / 64;
  // gemm1: A = [AGG | x], K=192, split=96, lda=96 -> H with relu+b1
  gemm_kernel<<<gemmBlocks, 256, 0, stream>>>(AGG, x, IN_DIM, IN_DIM, 192, S1, b1, H, HID, N, 0);
  // gemm2: A = H, K=128 -> TR ([T2|R2], b2 on cols>=64)
  gemm_kernel<<<gemmBlocks, 256, 0, stream>>>(H, H, HID, HID, HID, S2, b2, TR, HID, N, 1);

  final_kernel<<<nodeBlocks, 256, 0, stream>>>(TR, adj, rowptr, inv_deg, out, N);
}

// Round 2
// 409.553 us; speedup vs baseline: 1.3138x; 1.3138x over previous
//
#include <hip/hip_runtime.h>
#include <cstdint>
#include <cstddef>

// BinSAGE: 2-layer GraphSAGE with sign-binarized weights.
// N=50000 nodes, E=800000 edges, dims 96 -> 128 -> 64.
// Plan:
//   CSR build (count / 3-phase parallel scan / fill)
//   agg1 (mean of x over in-edges, 96 wide)
//   gemm1: [AGG1 | x] (K=192) @ S1 -> relu -> H [N,128]
//   gemm2: H @ S2 (K=128) -> [T2 | R2]
//   final: out = inv_deg * segsum(T2[src]) + R2   (aggregate AFTER transform: 64 wide)

#define N_NODES 50000
#define IN_DIM 96
#define HID 128
#define OUT_DIM 64
#define KC 16

static inline size_t alignUp(size_t v, size_t a) { return (v + a - 1) & ~(a - 1); }

__global__ void count_deg_kernel(const int* __restrict__ dst, int* __restrict__ deg, int E) {
  int e = blockIdx.x * blockDim.x + threadIdx.x;
  if (e < E) atomicAdd(&deg[dst[e]], 1);
}

// ---- 3-phase parallel exclusive scan of deg[0..N) ----
// Phase A: per-block (256 elems) sums
__global__ __launch_bounds__(256) void block_sum_kernel(const int* __restrict__ deg,
    int* __restrict__ blockSums, int n) {
  __shared__ int smem[256];
  const int t = threadIdx.x;
  const int i = blockIdx.x * 256 + t;
  smem[t] = (i < n) ? deg[i] : 0;
  __syncthreads();
  for (int off = 128; off > 0; off >>= 1) {
    if (t < off) smem[t] += smem[t + off];
    __syncthreads();
  }
  if (t == 0) blockSums[blockIdx.x] = smem[0];
}

// Phase B: single block scans <=256 block sums (exclusive offsets), writes total.
__global__ __launch_bounds__(256) void scan_blocksums_kernel(const int* __restrict__ blockSums,
    int* __restrict__ blockOffs, int* __restrict__ rowptr, int nB, int n) {
  __shared__ int smem[256];
  const int t = threadIdx.x;
  int v = (t < nB) ? blockSums[t] : 0;
  smem[t] = v;
  __syncthreads();
  for (int off = 1; off < 256; off <<= 1) {
    int u = (t >= off) ? smem[t - off] : 0;
    __syncthreads();
    smem[t] += u;
    __syncthreads();
  }
  if (t < nB) blockOffs[t] = smem[t] - v;  // exclusive
  if (t == 255) rowptr[n] = smem[255];     // total = E
}

// Phase C: per-block inclusive scan + offset -> rowptr/cursor/inv_deg
__global__ __launch_bounds__(256) void write_rowptr_kernel(const int* __restrict__ deg,
    const int* __restrict__ blockOffs, int* __restrict__ rowptr, int* __restrict__ cursor,
    float* __restrict__ inv_deg, int n) {
  __shared__ int smem[256];
  const int t = threadIdx.x;
  const int i = blockIdx.x * 256 + t;
  const int d = (i < n) ? deg[i] : 0;
  smem[t] = d;
  __syncthreads();
  for (int off = 1; off < 256; off <<= 1) {
    int u = (t >= off) ? smem[t - off] : 0;
    __syncthreads();
    smem[t] += u;
    __syncthreads();
  }
  if (i < n) {
    const int excl = smem[t] - d + blockOffs[blockIdx.x];
    rowptr[i] = excl;
    cursor[i] = excl;
    inv_deg[i] = 1.0f / (float)(d > 1 ? d : 1);
  }
}

__global__ void build_adj_kernel(const int* __restrict__ src, const int* __restrict__ dst,
    int* __restrict__ cursor, int* __restrict__ adj, int E) {
  int e = blockIdx.x * blockDim.x + threadIdx.x;
  if (e < E) {
    int slot = atomicAdd(&cursor[dst[e]], 1);
    adj[slot] = src[e];
  }
}

__device__ __forceinline__ float sgnf(float w) {
  return (w > 0.f) ? 1.f : ((w < 0.f) ? -1.f : 0.f);
}

// S1: [192][128] K-major: k<96 -> sgn(w1l[j][k]); k>=96 -> sgn(w1r[j][k-96])
// S2: [128][128] K-major: j<64 -> sgn(w2l[j][k]);  j>=64 -> sgn(w2r[j-64][k])
__global__ void prep_s_kernel(const float* __restrict__ w1l, const float* __restrict__ w1r,
                              const float* __restrict__ w2l, const float* __restrict__ w2r,
                              float* __restrict__ S1, float* __restrict__ S2) {
  int idx = blockIdx.x * blockDim.x + threadIdx.x;
  if (idx < 192 * 128) {
    int k = idx >> 7, j = idx & 127;
    float w = (k < 96) ? w1l[j * 96 + k] : w1r[j * 96 + (k - 96)];
    S1[idx] = sgnf(w);
  } else if (idx < 192 * 128 + 128 * 128) {
    int i2 = idx - 192 * 128;
    int k = i2 >> 7, j = i2 & 127;
    float w = (j < 64) ? w2l[j * 128 + k] : w2r[(j - 64) * 128 + k];
    S2[i2] = sgnf(w);
  }
}

// One wave per node: lane f accumulates x[src][f]; 96 = 64 + 32 features.
__global__ __launch_bounds__(256) void agg1_kernel(const float* __restrict__ x,
    const int* __restrict__ adj, const int* __restrict__ rowptr,
    const float* __restrict__ inv_deg, float* __restrict__ AGG, int nNodes) {
  const int wave = threadIdx.x >> 6;
  const int lane = threadIdx.x & 63;
  const int n = blockIdx.x * 4 + wave;
  if (n >= nNodes) return;
  const int beg = rowptr[n], end = rowptr[n + 1];
  float a0 = 0.f, a1 = 0.f;
  for (int e = beg; e < end; ++e) {
    const int s = adj[e];
    const float* xr = x + (size_t)s * IN_DIM;
    a0 += xr[lane];
    if (lane < 32) a1 += xr[64 + lane];
  }
  const float inv = inv_deg[n];
  AGG[(size_t)n * IN_DIM + lane] = a0 * inv;
  if (lane < 32) AGG[(size_t)n * IN_DIM + 64 + lane] = a1 * inv;
}

// Tiled f32 GEMM: C[M][128] = A[M][K] * B[K][128]  (B is K-major, n-contiguous)
// A element (row,k): k<split -> Aa[row*lda + k]; else Ab[row*lda + (k-split)]
// mode 0: C = relu(C + bias[col])          (gemm1, bias=b1[128])
// mode 1: col>=64 -> C += bias[col-64]     (gemm2, bias=b2[64])
__global__ __launch_bounds__(256) void gemm_kernel(
    const float* __restrict__ Aa, const float* __restrict__ Ab, int lda, int split, int K,
    const float* __restrict__ B, const float* __restrict__ bias,
    float* __restrict__ C, int ldc, int M, int mode) {
  __shared__ float As[KC][68];
  __shared__ float Bs[KC][132];
  const int tid = threadIdx.x;
  const int tx = tid & 15;   // col group: cols tx*8 .. +7
  const int ty = tid >> 4;   // row group: rows ty*4 .. +3
  const int rowBase = blockIdx.x * 64;

  float acc[4][8];
#pragma unroll
  for (int i = 0; i < 4; ++i)
#pragma unroll
    for (int j = 0; j < 8; ++j) acc[i][j] = 0.f;

  const int lm = tid >> 2;          // 0..63 row in tile
  const int lk = (tid & 3) * 4;     // 0,4,8,12
  const int arow = rowBase + lm;
  const bool aval = arow < M;
  const int bk = tid >> 4;          // 0..15
  const int bn = (tid & 15) * 8;    // 0..120

  for (int k0 = 0; k0 < K; k0 += KC) {
    const int kk = k0 + lk;
    float4 av = make_float4(0.f, 0.f, 0.f, 0.f);
    if (aval) {
      const float* Arow = (kk < split) ? (Aa + (size_t)arow * lda + kk)
                                       : (Ab + (size_t)arow * lda + (kk - split));
      av = *(const float4*)Arow;
    }
    const float4 bv0 = *(const float4*)(B + (size_t)(k0 + bk) * 128 + bn);
    const float4 bv1 = *(const float4*)(B + (size_t)(k0 + bk) * 128 + bn + 4);
    __syncthreads();
    As[lk + 0][lm] = av.x;
    As[lk + 1][lm] = av.y;
    As[lk + 2][lm] = av.z;
    As[lk + 3][lm] = av.w;
    *(float4*)&Bs[bk][bn] = bv0;
    *(float4*)&Bs[bk][bn + 4] = bv1;
    __syncthreads();
#pragma unroll
    for (int k = 0; k < KC; ++k) {
      const float4 a4 = *(const float4*)&As[k][ty * 4];
      const float4 b4a = *(const float4*)&Bs[k][tx * 8];
      const float4 b4b = *(const float4*)&Bs[k][tx * 8 + 4];
      const float aa[4] = {a4.x, a4.y, a4.z, a4.w};
      const float bb[8] = {b4a.x, b4a.y, b4a.z, b4a.w, b4b.x, b4b.y, b4b.z, b4b.w};
#pragma unroll
      for (int i = 0; i < 4; ++i)
#pragma unroll
        for (int j = 0; j < 8; ++j) acc[i][j] = fmaf(aa[i], bb[j], acc[i][j]);
    }
  }

#pragma unroll
  for (int i = 0; i < 4; ++i) {
    const int r = rowBase + ty * 4 + i;
    if (r < M) {
      float o[8];
#pragma unroll
      for (int j = 0; j < 8; ++j) {
        float c = acc[i][j];
        const int col = tx * 8 + j;
        if (mode == 0) {
          c += bias[col];
          c = fmaxf(c, 0.f);
        } else {
          if (col >= 64) c += bias[col - 64];
        }
        o[j] = c;
      }
      float* Crow = C + (size_t)r * ldc + tx * 8;
      *(float4*)Crow = make_float4(o[0], o[1], o[2], o[3]);
      *(float4*)(Crow + 4) = make_float4(o[4], o[5], o[6], o[7]);
    }
  }
}

// out[n][c] = inv_deg[n] * sum_{e in CSR(n)} T2[src_e][c] + R2[n][c],  c<64
__global__ __launch_bounds__(256) void final_kernel(const float* __restrict__ TR,
    const int* __restrict__ adj, const int* __restrict__ rowptr,
    const float* __restrict__ inv_deg, float* __restrict__ out, int nNodes) {
  const int wave = threadIdx.x >> 6;
  const int lane = threadIdx.x & 63;
  const int n = blockIdx.x * 4 + wave;
  if (n >= nNodes) return;
  const int beg = rowptr[n], end = rowptr[n + 1];
  float acc = 0.f;
  for (int e = beg; e < end; ++e) {
    const int s = adj[e];
    acc += TR[(size_t)s * 128 + lane];
  }
  out[(size_t)n * 64 + lane] = acc * inv_deg[n] + TR[(size_t)n * 128 + 64 + lane];
}

extern "C" void kernel_launch(void* const* d_in, const int* in_sizes, int n_in,
                              void* d_out, int out_size, void* d_ws, size_t ws_size,
                              hipStream_t stream) {
  const float* x   = (const float*)d_in[0];
  const int*   ei  = (const int*)d_in[1];
  const float* w1l = (const float*)d_in[2];
  const float* b1  = (const float*)d_in[3];
  const float* w1r = (const float*)d_in[4];
  const float* w2l = (const float*)d_in[5];
  const float* b2  = (const float*)d_in[6];
  const float* w2r = (const float*)d_in[7];
  float* out = (float*)d_out;

  const int N = in_sizes[0] / IN_DIM;   // 50000
  const int E = in_sizes[1] / 2;        // 800000
  const int* src = ei;
  const int* dst = ei + E;

  // ---- workspace carve (all 256B aligned) ----
  char* p = (char*)d_ws;
  float* AGG = (float*)p;   // [N][96], reused as TR [N][128]
  float* TR  = (float*)p;
  p += alignUp((size_t)N * 128 * sizeof(float), 256);
  float* H = (float*)p;  p += alignUp((size_t)N * HID * sizeof(float), 256);
  float* S1 = (float*)p; p += alignUp(192 * 128 * sizeof(float), 256);
  float* S2 = (float*)p; p += alignUp(128 * 128 * sizeof(float), 256);
  int* deg = (int*)p;    p += alignUp((size_t)N * sizeof(int), 256);
  int* rowptr = (int*)p; p += alignUp((size_t)(N + 1) * sizeof(int), 256);
  int* cursor = (int*)p; p += alignUp((size_t)N * sizeof(int), 256);
  float* inv_deg = (float*)p; p += alignUp((size_t)N * sizeof(float), 256);
  int* adj = (int*)p;    p += alignUp((size_t)E * sizeof(int), 256);
  int* blockSums = (int*)p; p += alignUp(512 * sizeof(int), 256);
  int* blockOffs = (int*)p; p += alignUp(512 * sizeof(int), 256);
  (void)ws_size; (void)n_in; (void)out_size;

  hipMemsetAsync(deg, 0, (size_t)N * sizeof(int), stream);

  const int eBlocks = (E + 255) / 256;
  count_deg_kernel<<<eBlocks, 256, 0, stream>>>(dst, deg, E);

  // 3-phase parallel scan (N=50000 -> 196 blocks <= 256)
  const int sBlocks = (N + 255) / 256;
  block_sum_kernel<<<sBlocks, 256, 0, stream>>>(deg, blockSums, N);
  scan_blocksums_kernel<<<1, 256, 0, stream>>>(blockSums, blockOffs, rowptr, sBlocks, N);
  write_rowptr_kernel<<<sBlocks, 256, 0, stream>>>(deg, blockOffs, rowptr, cursor, inv_deg, N);

  build_adj_kernel<<<eBlocks, 256, 0, stream>>>(src, dst, cursor, adj, E);

  prep_s_kernel<<<(192 * 128 + 128 * 128 + 255) / 256, 256, 0, stream>>>(w1l, w1r, w2l, w2r, S1, S2);

  const int nodeBlocks = (N + 3) / 4;
  agg1_kernel<<<nodeBlocks, 256, 0, stream>>>(x, adj, rowptr, inv_deg, AGG, N);

  const int gemmBlocks = (N + 63) / 64;
  gemm_kernel<<<gemmBlocks, 256, 0, stream>>>(AGG, x, IN_DIM, IN_DIM, 192, S1, b1, H, HID, N, 0);
  gemm_kernel<<<gemmBlocks, 256, 0, stream>>>(H, H, HID, HID, HID, S2, b2, TR, HID, N, 1);

  final_kernel<<<nodeBlocks, 256, 0, stream>>>(TR, adj, rowptr, inv_deg, out, N);
}

// Round 3
// 335.417 us; speedup vs baseline: 1.6042x; 1.2210x over previous
//
#include <hip/hip_runtime.h>
#include <cstdint>
#include <cstddef>

// BinSAGE: 2-layer GraphSAGE with sign-binarized weights.
// N=50000 nodes, E=800000 edges, dims 96 -> 128 -> 64.
//   CSR build (count / 3-phase scan / fill)
//   xb = bf16(x)                      [N,96]  (192 B rows -> half gather bytes)
//   agg1: mean of xb over in-edges -> AGG f32 [N,96]
//   gemm1: [AGG | x] (K=192) @ S1 -> relu -> H [N,128]
//   gemm2: H @ S2 (K=128) -> T2b bf16 [N,64] + R2 f32 [N,64] (+b2)
//   final: out = inv_deg * segsum(T2b[src]) + R2    (gather 128 B bf16 rows)

#define N_NODES 50000
#define IN_DIM 96
#define HID 128
#define OUT_DIM 64
#define KC 16

static inline size_t alignUp(size_t v, size_t a) { return (v + a - 1) & ~(a - 1); }

__device__ __forceinline__ uint16_t f2bf(float f) {
  uint32_t u = __float_as_uint(f);
  return (uint16_t)((u + 0x7FFF + ((u >> 16) & 1)) >> 16);
}
__device__ __forceinline__ float bflo(uint32_t v) { return __uint_as_float(v << 16); }
__device__ __forceinline__ float bfhi(uint32_t v) { return __uint_as_float(v & 0xFFFF0000u); }
__device__ __forceinline__ float bf1(uint16_t v) { return __uint_as_float((uint32_t)v << 16); }

__global__ void count_deg_kernel(const int* __restrict__ dst, int* __restrict__ deg, int E) {
  int e = blockIdx.x * blockDim.x + threadIdx.x;
  if (e < E) atomicAdd(&deg[dst[e]], 1);
}

__global__ __launch_bounds__(256) void block_sum_kernel(const int* __restrict__ deg,
    int* __restrict__ blockSums, int n) {
  __shared__ int smem[256];
  const int t = threadIdx.x;
  const int i = blockIdx.x * 256 + t;
  smem[t] = (i < n) ? deg[i] : 0;
  __syncthreads();
  for (int off = 128; off > 0; off >>= 1) {
    if (t < off) smem[t] += smem[t + off];
    __syncthreads();
  }
  if (t == 0) blockSums[blockIdx.x] = smem[0];
}

__global__ __launch_bounds__(256) void scan_blocksums_kernel(const int* __restrict__ blockSums,
    int* __restrict__ blockOffs, int* __restrict__ rowptr, int nB, int n) {
  __shared__ int smem[256];
  const int t = threadIdx.x;
  int v = (t < nB) ? blockSums[t] : 0;
  smem[t] = v;
  __syncthreads();
  for (int off = 1; off < 256; off <<= 1) {
    int u = (t >= off) ? smem[t - off] : 0;
    __syncthreads();
    smem[t] += u;
    __syncthreads();
  }
  if (t < nB) blockOffs[t] = smem[t] - v;
  if (t == 255) rowptr[n] = smem[255];
}

__global__ __launch_bounds__(256) void write_rowptr_kernel(const int* __restrict__ deg,
    const int* __restrict__ blockOffs, int* __restrict__ rowptr, int* __restrict__ cursor,
    float* __restrict__ inv_deg, int n) {
  __shared__ int smem[256];
  const int t = threadIdx.x;
  const int i = blockIdx.x * 256 + t;
  const int d = (i < n) ? deg[i] : 0;
  smem[t] = d;
  __syncthreads();
  for (int off = 1; off < 256; off <<= 1) {
    int u = (t >= off) ? smem[t - off] : 0;
    __syncthreads();
    smem[t] += u;
    __syncthreads();
  }
  if (i < n) {
    const int excl = smem[t] - d + blockOffs[blockIdx.x];
    rowptr[i] = excl;
    cursor[i] = excl;
    inv_deg[i] = 1.0f / (float)(d > 1 ? d : 1);
  }
}

__global__ void build_adj_kernel(const int* __restrict__ src, const int* __restrict__ dst,
    int* __restrict__ cursor, int* __restrict__ adj, int E) {
  int e = blockIdx.x * blockDim.x + threadIdx.x;
  if (e < E) {
    int slot = atomicAdd(&cursor[dst[e]], 1);
    adj[slot] = src[e];
  }
}

__device__ __forceinline__ float sgnf(float w) {
  return (w > 0.f) ? 1.f : ((w < 0.f) ? -1.f : 0.f);
}

__global__ void prep_s_kernel(const float* __restrict__ w1l, const float* __restrict__ w1r,
                              const float* __restrict__ w2l, const float* __restrict__ w2r,
                              float* __restrict__ S1, float* __restrict__ S2) {
  int idx = blockIdx.x * blockDim.x + threadIdx.x;
  if (idx < 192 * 128) {
    int k = idx >> 7, j = idx & 127;
    float w = (k < 96) ? w1l[j * 96 + k] : w1r[j * 96 + (k - 96)];
    S1[idx] = sgnf(w);
  } else if (idx < 192 * 128 + 128 * 128) {
    int i2 = idx - 192 * 128;
    int k = i2 >> 7, j = i2 & 127;
    float w = (j < 64) ? w2l[j * 128 + k] : w2r[(j - 64) * 128 + k];
    S2[i2] = sgnf(w);
  }
}

// x (f32) -> xb (bf16), 4 elems/thread
__global__ __launch_bounds__(256) void prep_xb_kernel(const float* __restrict__ x,
    uint16_t* __restrict__ xb, int total4) {
  int i = blockIdx.x * blockDim.x + threadIdx.x;
  if (i < total4) {
    float4 v = *(const float4*)(x + (size_t)i * 4);
    uint32_t p0 = (uint32_t)f2bf(v.x) | ((uint32_t)f2bf(v.y) << 16);
    uint32_t p1 = (uint32_t)f2bf(v.z) | ((uint32_t)f2bf(v.w) << 16);
    *(uint2*)(xb + (size_t)i * 4) = make_uint2(p0, p1);
  }
}

// One wave per node; lanes 0..47 own feature pairs (ushort2). Edge loop unrolled x4.
__global__ __launch_bounds__(256) void agg1_kernel(const uint16_t* __restrict__ xb,
    const int* __restrict__ adj, const int* __restrict__ rowptr,
    const float* __restrict__ inv_deg, float* __restrict__ AGG, int nNodes) {
  const int wave = threadIdx.x >> 6;
  const int lane = threadIdx.x & 63;
  const int n = blockIdx.x * 4 + wave;
  if (n >= nNodes) return;
  const int beg = rowptr[n], end = rowptr[n + 1];
  const bool act = lane < 48;
  const int off = lane * 2;
  float a0 = 0.f, a1 = 0.f;
  int e = beg;
  for (; e + 4 <= end; e += 4) {
    const int s0 = adj[e], s1 = adj[e + 1], s2 = adj[e + 2], s3 = adj[e + 3];
    uint32_t v0 = 0, v1 = 0, v2 = 0, v3 = 0;
    if (act) {
      v0 = *(const uint32_t*)(xb + (size_t)s0 * IN_DIM + off);
      v1 = *(const uint32_t*)(xb + (size_t)s1 * IN_DIM + off);
      v2 = *(const uint32_t*)(xb + (size_t)s2 * IN_DIM + off);
      v3 = *(const uint32_t*)(xb + (size_t)s3 * IN_DIM + off);
    }
    a0 += (bflo(v0) + bflo(v1)) + (bflo(v2) + bflo(v3));
    a1 += (bfhi(v0) + bfhi(v1)) + (bfhi(v2) + bfhi(v3));
  }
  for (; e < end; ++e) {
    const int s = adj[e];
    uint32_t v = 0;
    if (act) v = *(const uint32_t*)(xb + (size_t)s * IN_DIM + off);
    a0 += bflo(v);
    a1 += bfhi(v);
  }
  if (act) {
    const float inv = inv_deg[n];
    *(float2*)(AGG + (size_t)n * IN_DIM + off) = make_float2(a0 * inv, a1 * inv);
  }
}

// Tiled f32 GEMM: C[M][128] = A[M][K] * B[K][128]  (B K-major, n-contiguous)
// mode 0: C_f32 = relu(acc + bias[col])                      -> Cf [M,128]
// mode 1: col<64 -> T2b bf16[r][col]; col>=64 -> R2 f32[r][col-64] = acc + bias[col-64]
__global__ __launch_bounds__(256) void gemm_kernel(
    const float* __restrict__ Aa, const float* __restrict__ Ab, int lda, int split, int K,
    const float* __restrict__ B, const float* __restrict__ bias,
    float* __restrict__ Cf, uint16_t* __restrict__ T2b, float* __restrict__ R2,
    int M, int mode) {
  __shared__ float As[KC][68];
  __shared__ float Bs[KC][132];
  const int tid = threadIdx.x;
  const int tx = tid & 15;
  const int ty = tid >> 4;
  const int rowBase = blockIdx.x * 64;

  float acc[4][8];
#pragma unroll
  for (int i = 0; i < 4; ++i)
#pragma unroll
    for (int j = 0; j < 8; ++j) acc[i][j] = 0.f;

  const int lm = tid >> 2;
  const int lk = (tid & 3) * 4;
  const int arow = rowBase + lm;
  const bool aval = arow < M;
  const int bk = tid >> 4;
  const int bn = (tid & 15) * 8;

  for (int k0 = 0; k0 < K; k0 += KC) {
    const int kk = k0 + lk;
    float4 av = make_float4(0.f, 0.f, 0.f, 0.f);
    if (aval) {
      const float* Arow = (kk < split) ? (Aa + (size_t)arow * lda + kk)
                                       : (Ab + (size_t)arow * lda + (kk - split));
      av = *(const float4*)Arow;
    }
    const float4 bv0 = *(const float4*)(B + (size_t)(k0 + bk) * 128 + bn);
    const float4 bv1 = *(const float4*)(B + (size_t)(k0 + bk) * 128 + bn + 4);
    __syncthreads();
    As[lk + 0][lm] = av.x;
    As[lk + 1][lm] = av.y;
    As[lk + 2][lm] = av.z;
    As[lk + 3][lm] = av.w;
    *(float4*)&Bs[bk][bn] = bv0;
    *(float4*)&Bs[bk][bn + 4] = bv1;
    __syncthreads();
#pragma unroll
    for (int k = 0; k < KC; ++k) {
      const float4 a4 = *(const float4*)&As[k][ty * 4];
      const float4 b4a = *(const float4*)&Bs[k][tx * 8];
      const float4 b4b = *(const float4*)&Bs[k][tx * 8 + 4];
      const float aa[4] = {a4.x, a4.y, a4.z, a4.w};
      const float bb[8] = {b4a.x, b4a.y, b4a.z, b4a.w, b4b.x, b4b.y, b4b.z, b4b.w};
#pragma unroll
      for (int i = 0; i < 4; ++i)
#pragma unroll
        for (int j = 0; j < 8; ++j) acc[i][j] = fmaf(aa[i], bb[j], acc[i][j]);
    }
  }

#pragma unroll
  for (int i = 0; i < 4; ++i) {
    const int r = rowBase + ty * 4 + i;
    if (r < M) {
      if (mode == 0) {
        float o[8];
#pragma unroll
        for (int j = 0; j < 8; ++j) o[j] = fmaxf(acc[i][j] + bias[tx * 8 + j], 0.f);
        float* Crow = Cf + (size_t)r * 128 + tx * 8;
        *(float4*)Crow = make_float4(o[0], o[1], o[2], o[3]);
        *(float4*)(Crow + 4) = make_float4(o[4], o[5], o[6], o[7]);
      } else if (tx < 8) {
        // cols 0..63 -> T2 bf16
        uint32_t p[4];
#pragma unroll
        for (int j = 0; j < 4; ++j)
          p[j] = (uint32_t)f2bf(acc[i][2 * j]) | ((uint32_t)f2bf(acc[i][2 * j + 1]) << 16);
        *(uint4*)(T2b + (size_t)r * 64 + tx * 8) = make_uint4(p[0], p[1], p[2], p[3]);
      } else {
        // cols 64..127 -> R2 f32 (+b2)
        const int c = (tx - 8) * 8;
        float o[8];
#pragma unroll
        for (int j = 0; j < 8; ++j) o[j] = acc[i][j] + bias[c + j];
        float* Rrow = R2 + (size_t)r * 64 + c;
        *(float4*)Rrow = make_float4(o[0], o[1], o[2], o[3]);
        *(float4*)(Rrow + 4) = make_float4(o[4], o[5], o[6], o[7]);
      }
    }
  }
}

// out[n][c] = inv_deg[n] * sum_e bf16(T2b[src_e][c]) + R2[n][c]; lane=c (64 cols)
__global__ __launch_bounds__(256) void final_kernel(const uint16_t* __restrict__ T2b,
    const float* __restrict__ R2, const int* __restrict__ adj, const int* __restrict__ rowptr,
    const float* __restrict__ inv_deg, float* __restrict__ out, int nNodes) {
  const int wave = threadIdx.x >> 6;
  const int lane = threadIdx.x & 63;
  const int n = blockIdx.x * 4 + wave;
  if (n >= nNodes) return;
  const int beg = rowptr[n], end = rowptr[n + 1];
  float acc = 0.f;
  int e = beg;
  for (; e + 4 <= end; e += 4) {
    const int s0 = adj[e], s1 = adj[e + 1], s2 = adj[e + 2], s3 = adj[e + 3];
    const float f0 = bf1(T2b[(size_t)s0 * 64 + lane]);
    const float f1 = bf1(T2b[(size_t)s1 * 64 + lane]);
    const float f2 = bf1(T2b[(size_t)s2 * 64 + lane]);
    const float f3 = bf1(T2b[(size_t)s3 * 64 + lane]);
    acc += (f0 + f1) + (f2 + f3);
  }
  for (; e < end; ++e) acc += bf1(T2b[(size_t)adj[e] * 64 + lane]);
  out[(size_t)n * 64 + lane] = acc * inv_deg[n] + R2[(size_t)n * 64 + lane];
}

extern "C" void kernel_launch(void* const* d_in, const int* in_sizes, int n_in,
                              void* d_out, int out_size, void* d_ws, size_t ws_size,
                              hipStream_t stream) {
  const float* x   = (const float*)d_in[0];
  const int*   ei  = (const int*)d_in[1];
  const float* w1l = (const float*)d_in[2];
  const float* b1  = (const float*)d_in[3];
  const float* w1r = (const float*)d_in[4];
  const float* w2l = (const float*)d_in[5];
  const float* b2  = (const float*)d_in[6];
  const float* w2r = (const float*)d_in[7];
  float* out = (float*)d_out;

  const int N = in_sizes[0] / IN_DIM;   // 50000
  const int E = in_sizes[1] / 2;        // 800000
  const int* src = ei;
  const int* dst = ei + E;

  // ---- workspace carve ----
  // Region A (19.2 MB): AGG [N,96] f32 until gemm1; then T2b [N,64] bf16 + R2 [N,64] f32.
  char* p = (char*)d_ws;
  float* AGG = (float*)p;
  uint16_t* T2b = (uint16_t*)p;
  float* R2 = (float*)(p + (size_t)N * 64 * sizeof(uint16_t));
  p += alignUp((size_t)N * IN_DIM * sizeof(float), 256);
  float* H = (float*)p;  p += alignUp((size_t)N * HID * sizeof(float), 256);
  uint16_t* xb = (uint16_t*)p; p += alignUp((size_t)N * IN_DIM * sizeof(uint16_t), 256);
  float* S1 = (float*)p; p += alignUp(192 * 128 * sizeof(float), 256);
  float* S2 = (float*)p; p += alignUp(128 * 128 * sizeof(float), 256);
  int* deg = (int*)p;    p += alignUp((size_t)N * sizeof(int), 256);
  int* rowptr = (int*)p; p += alignUp((size_t)(N + 1) * sizeof(int), 256);
  int* cursor = (int*)p; p += alignUp((size_t)N * sizeof(int), 256);
  float* inv_deg = (float*)p; p += alignUp((size_t)N * sizeof(float), 256);
  int* adj = (int*)p;    p += alignUp((size_t)E * sizeof(int), 256);
  int* blockSums = (int*)p; p += alignUp(512 * sizeof(int), 256);
  int* blockOffs = (int*)p; p += alignUp(512 * sizeof(int), 256);
  (void)ws_size; (void)n_in; (void)out_size;

  hipMemsetAsync(deg, 0, (size_t)N * sizeof(int), stream);

  const int eBlocks = (E + 255) / 256;
  count_deg_kernel<<<eBlocks, 256, 0, stream>>>(dst, deg, E);

  const int sBlocks = (N + 255) / 256;
  block_sum_kernel<<<sBlocks, 256, 0, stream>>>(deg, blockSums, N);
  scan_blocksums_kernel<<<1, 256, 0, stream>>>(blockSums, blockOffs, rowptr, sBlocks, N);
  write_rowptr_kernel<<<sBlocks, 256, 0, stream>>>(deg, blockOffs, rowptr, cursor, inv_deg, N);

  build_adj_kernel<<<eBlocks, 256, 0, stream>>>(src, dst, cursor, adj, E);

  prep_s_kernel<<<(192 * 128 + 128 * 128 + 255) / 256, 256, 0, stream>>>(w1l, w1r, w2l, w2r, S1, S2);
  prep_xb_kernel<<<((N * IN_DIM / 4) + 255) / 256, 256, 0, stream>>>(x, xb, N * IN_DIM / 4);

  const int nodeBlocks = (N + 3) / 4;
  agg1_kernel<<<nodeBlocks, 256, 0, stream>>>(xb, adj, rowptr, inv_deg, AGG, N);

  const int gemmBlocks = (N + 63) / 64;
  gemm_kernel<<<gemmBlocks, 256, 0, stream>>>(AGG, x, IN_DIM, IN_DIM, 192, S1, b1,
                                              H, nullptr, nullptr, N, 0);
  gemm_kernel<<<gemmBlocks, 256, 0, stream>>>(H, H, HID, HID, HID, S2, b2,
                                              nullptr, T2b, R2, N, 1);

  final_kernel<<<nodeBlocks, 256, 0, stream>>>(T2b, R2, adj, rowptr, inv_deg, out, N);
}

// Round 4
// 299.476 us; speedup vs baseline: 1.7968x; 1.1200x over previous
//
#include <hip/hip_runtime.h>
#include <cstdint>
#include <cstddef>

// BinSAGE: 2-layer GraphSAGE with sign-binarized weights. MFMA bf16 edition.
// N=50000 nodes, E=800000 edges, dims 96 -> 128 -> 64.
//   CSR build (count / 3-phase scan / fill)
//   xb = bf16(x) [N,96]; agg1: mean of xb -> AGGb bf16 [N,96]
//   gemm1 (MFMA): [AGGb | xb] (K=192) @ S1t^T -> relu -> Hb bf16 [N,128]
//   gemm2 (MFMA): Hb (K=128) @ S2t^T -> T2b bf16 [N,64] + R2 f32 [N,64] (+b2)
//   final: out = inv_deg * segsum(T2b[src]) + R2
// GEMM design: no LDS. Wave = 16 rows x 128 cols, A-frags and B-frags loaded
// register-direct from global (B is 49 KB, L2-resident; A-frag pattern is
// 16 rows x 64 B lines). 8 MFMA per k-step, no barriers, no bank conflicts.

#define N_NODES 50000
#define IN_DIM 96
#define HID 128
#define OUT_DIM 64

typedef __attribute__((ext_vector_type(8))) short bf16x8;
typedef __attribute__((ext_vector_type(4))) float f32x4;

static inline size_t alignUp(size_t v, size_t a) { return (v + a - 1) & ~(a - 1); }

__device__ __forceinline__ uint16_t f2bf(float f) {
  uint32_t u = __float_as_uint(f);
  return (uint16_t)((u + 0x7FFF + ((u >> 16) & 1)) >> 16);
}
__device__ __forceinline__ float bflo(uint32_t v) { return __uint_as_float(v << 16); }
__device__ __forceinline__ float bfhi(uint32_t v) { return __uint_as_float(v & 0xFFFF0000u); }
__device__ __forceinline__ float bf1(uint16_t v) { return __uint_as_float((uint32_t)v << 16); }

__global__ void count_deg_kernel(const int* __restrict__ dst, int* __restrict__ deg, int E) {
  int e = blockIdx.x * blockDim.x + threadIdx.x;
  if (e < E) atomicAdd(&deg[dst[e]], 1);
}

__global__ __launch_bounds__(256) void block_sum_kernel(const int* __restrict__ deg,
    int* __restrict__ blockSums, int n) {
  __shared__ int smem[256];
  const int t = threadIdx.x;
  const int i = blockIdx.x * 256 + t;
  smem[t] = (i < n) ? deg[i] : 0;
  __syncthreads();
  for (int off = 128; off > 0; off >>= 1) {
    if (t < off) smem[t] += smem[t + off];
    __syncthreads();
  }
  if (t == 0) blockSums[blockIdx.x] = smem[0];
}

__global__ __launch_bounds__(256) void scan_blocksums_kernel(const int* __restrict__ blockSums,
    int* __restrict__ blockOffs, int* __restrict__ rowptr, int nB, int n) {
  __shared__ int smem[256];
  const int t = threadIdx.x;
  int v = (t < nB) ? blockSums[t] : 0;
  smem[t] = v;
  __syncthreads();
  for (int off = 1; off < 256; off <<= 1) {
    int u = (t >= off) ? smem[t - off] : 0;
    __syncthreads();
    smem[t] += u;
    __syncthreads();
  }
  if (t < nB) blockOffs[t] = smem[t] - v;
  if (t == 255) rowptr[n] = smem[255];
}

__global__ __launch_bounds__(256) void write_rowptr_kernel(const int* __restrict__ deg,
    const int* __restrict__ blockOffs, int* __restrict__ rowptr, int* __restrict__ cursor,
    float* __restrict__ inv_deg, int n) {
  __shared__ int smem[256];
  const int t = threadIdx.x;
  const int i = blockIdx.x * 256 + t;
  const int d = (i < n) ? deg[i] : 0;
  smem[t] = d;
  __syncthreads();
  for (int off = 1; off < 256; off <<= 1) {
    int u = (t >= off) ? smem[t - off] : 0;
    __syncthreads();
    smem[t] += u;
    __syncthreads();
  }
  if (i < n) {
    const int excl = smem[t] - d + blockOffs[blockIdx.x];
    rowptr[i] = excl;
    cursor[i] = excl;
    inv_deg[i] = 1.0f / (float)(d > 1 ? d : 1);
  }
}

__global__ void build_adj_kernel(const int* __restrict__ src, const int* __restrict__ dst,
    int* __restrict__ cursor, int* __restrict__ adj, int E) {
  int e = blockIdx.x * blockDim.x + threadIdx.x;
  if (e < E) {
    int slot = atomicAdd(&cursor[dst[e]], 1);
    adj[slot] = src[e];
  }
}

__device__ __forceinline__ uint16_t sgnbf(float w) {
  return (w > 0.f) ? (uint16_t)0x3F80 : ((w < 0.f) ? (uint16_t)0xBF80 : (uint16_t)0);
}

// Sign matrices, bf16, n-major (k-contiguous) so B-frag loads are 16B rows.
// S1t [128][192]: k<96 -> sgn(w1l[n][k]); k>=96 -> sgn(w1r[n][k-96])
// S2t [128][128]: n<64 -> sgn(w2l[n][k]); n>=64 -> sgn(w2r[n-64][k])
__global__ void prep_s_kernel(const float* __restrict__ w1l, const float* __restrict__ w1r,
                              const float* __restrict__ w2l, const float* __restrict__ w2r,
                              uint16_t* __restrict__ S1t, uint16_t* __restrict__ S2t) {
  int idx = blockIdx.x * blockDim.x + threadIdx.x;
  if (idx < 128 * 192) {
    int n = idx / 192, k = idx - n * 192;
    float w = (k < 96) ? w1l[n * 96 + k] : w1r[n * 96 + (k - 96)];
    S1t[idx] = sgnbf(w);
  } else if (idx < 128 * 192 + 128 * 128) {
    int i2 = idx - 128 * 192;
    int n = i2 >> 7, k = i2 & 127;
    float w = (n < 64) ? w2l[n * 128 + k] : w2r[(n - 64) * 128 + k];
    S2t[i2] = sgnbf(w);
  }
}

// x (f32) -> xb (bf16), 4 elems/thread
__global__ __launch_bounds__(256) void prep_xb_kernel(const float* __restrict__ x,
    uint16_t* __restrict__ xb, int total4) {
  int i = blockIdx.x * blockDim.x + threadIdx.x;
  if (i < total4) {
    float4 v = *(const float4*)(x + (size_t)i * 4);
    uint32_t p0 = (uint32_t)f2bf(v.x) | ((uint32_t)f2bf(v.y) << 16);
    uint32_t p1 = (uint32_t)f2bf(v.z) | ((uint32_t)f2bf(v.w) << 16);
    *(uint2*)(xb + (size_t)i * 4) = make_uint2(p0, p1);
  }
}

// One wave per node; lanes 0..47 own feature pairs. Edge loop unrolled x4.
// Output bf16 (AGGb).
__global__ __launch_bounds__(256) void agg1_kernel(const uint16_t* __restrict__ xb,
    const int* __restrict__ adj, const int* __restrict__ rowptr,
    const float* __restrict__ inv_deg, uint16_t* __restrict__ AGGb, int nNodes) {
  const int wave = threadIdx.x >> 6;
  const int lane = threadIdx.x & 63;
  const int n = blockIdx.x * 4 + wave;
  if (n >= nNodes) return;
  const int beg = rowptr[n], end = rowptr[n + 1];
  const bool act = lane < 48;
  const int off = lane * 2;
  float a0 = 0.f, a1 = 0.f;
  int e = beg;
  for (; e + 4 <= end; e += 4) {
    const int s0 = adj[e], s1 = adj[e + 1], s2 = adj[e + 2], s3 = adj[e + 3];
    uint32_t v0 = 0, v1 = 0, v2 = 0, v3 = 0;
    if (act) {
      v0 = *(const uint32_t*)(xb + (size_t)s0 * IN_DIM + off);
      v1 = *(const uint32_t*)(xb + (size_t)s1 * IN_DIM + off);
      v2 = *(const uint32_t*)(xb + (size_t)s2 * IN_DIM + off);
      v3 = *(const uint32_t*)(xb + (size_t)s3 * IN_DIM + off);
    }
    a0 += (bflo(v0) + bflo(v1)) + (bflo(v2) + bflo(v3));
    a1 += (bfhi(v0) + bfhi(v1)) + (bfhi(v2) + bfhi(v3));
  }
  for (; e < end; ++e) {
    const int s = adj[e];
    uint32_t v = 0;
    if (act) v = *(const uint32_t*)(xb + (size_t)s * IN_DIM + off);
    a0 += bflo(v);
    a1 += bfhi(v);
  }
  if (act) {
    const float inv = inv_deg[n];
    uint32_t pk = (uint32_t)f2bf(a0 * inv) | ((uint32_t)f2bf(a1 * inv) << 16);
    *(uint32_t*)(AGGb + (size_t)n * IN_DIM + off) = pk;
  }
}

// MFMA GEMM, no LDS. Block = 4 waves = 64 rows; wave = 16 rows x 128 cols.
// A[row][k] bf16: k<split -> Aa[row*lda+k], else Ab[row*lda+(k-split)]
// Bt [128][K] bf16 n-major.  C[row][col] = sum_k A[row][k]*Bt[col][k].
// mode 0: Hb[row*128+col] = bf16(relu(acc + bias[col]))
// mode 1: col<64 -> T2b[row*64+col] = bf16(acc); col>=64 -> R2[row*64+col-64] = acc + bias[col-64]
__global__ __launch_bounds__(256) void gemm_mfma_kernel(
    const uint16_t* __restrict__ Aa, const uint16_t* __restrict__ Ab,
    int lda, int split, int K,
    const uint16_t* __restrict__ Bt, const float* __restrict__ bias,
    uint16_t* __restrict__ Hb, uint16_t* __restrict__ T2b, float* __restrict__ R2,
    int M, int mode) {
  const int tid = threadIdx.x;
  const int wv = tid >> 6;
  const int lane = tid & 63;
  const int m16 = lane & 15;
  const int quad = lane >> 4;
  const int rowBase = blockIdx.x * 64 + wv * 16;
  int arow = rowBase + m16;
  if (arow >= M) arow = M - 1;  // clamp; stores are guarded

  f32x4 acc[8];
#pragma unroll
  for (int cf = 0; cf < 8; ++cf) acc[cf] = (f32x4){0.f, 0.f, 0.f, 0.f};

  const int kq = quad * 8;
  for (int k0 = 0; k0 < K; k0 += 32) {
    const int k = k0 + kq;
    const uint16_t* ap = (k < split) ? (Aa + (size_t)arow * lda + k)
                                     : (Ab + (size_t)arow * lda + (k - split));
    const bf16x8 a = *(const bf16x8*)ap;
    bf16x8 b[8];
#pragma unroll
    for (int cf = 0; cf < 8; ++cf)
      b[cf] = *(const bf16x8*)(Bt + (size_t)(cf * 16 + m16) * K + k);
#pragma unroll
    for (int cf = 0; cf < 8; ++cf)
      acc[cf] = __builtin_amdgcn_mfma_f32_16x16x32_bf16(a, b[cf], acc[cf], 0, 0, 0);
  }

#pragma unroll
  for (int cf = 0; cf < 8; ++cf) {
    const int col = cf * 16 + m16;
#pragma unroll
    for (int r = 0; r < 4; ++r) {
      const int row = rowBase + quad * 4 + r;
      if (row < M) {
        float v = acc[cf][r];
        if (mode == 0) {
          v = fmaxf(v + bias[col], 0.f);
          Hb[(size_t)row * 128 + col] = f2bf(v);
        } else if (col < 64) {
          T2b[(size_t)row * 64 + col] = f2bf(v);
        } else {
          R2[(size_t)row * 64 + (col - 64)] = v + bias[col - 64];
        }
      }
    }
  }
}

// out[n][c] = inv_deg[n] * sum_e bf16(T2b[src_e][c]) + R2[n][c]; lane=c (64 cols)
__global__ __launch_bounds__(256) void final_kernel(const uint16_t* __restrict__ T2b,
    const float* __restrict__ R2, const int* __restrict__ adj, const int* __restrict__ rowptr,
    const float* __restrict__ inv_deg, float* __restrict__ out, int nNodes) {
  const int wave = threadIdx.x >> 6;
  const int lane = threadIdx.x & 63;
  const int n = blockIdx.x * 4 + wave;
  if (n >= nNodes) return;
  const int beg = rowptr[n], end = rowptr[n + 1];
  float acc = 0.f;
  int e = beg;
  for (; e + 4 <= end; e += 4) {
    const int s0 = adj[e], s1 = adj[e + 1], s2 = adj[e + 2], s3 = adj[e + 3];
    const float f0 = bf1(T2b[(size_t)s0 * 64 + lane]);
    const float f1 = bf1(T2b[(size_t)s1 * 64 + lane]);
    const float f2 = bf1(T2b[(size_t)s2 * 64 + lane]);
    const float f3 = bf1(T2b[(size_t)s3 * 64 + lane]);
    acc += (f0 + f1) + (f2 + f3);
  }
  for (; e < end; ++e) acc += bf1(T2b[(size_t)adj[e] * 64 + lane]);
  out[(size_t)n * 64 + lane] = acc * inv_deg[n] + R2[(size_t)n * 64 + lane];
}

extern "C" void kernel_launch(void* const* d_in, const int* in_sizes, int n_in,
                              void* d_out, int out_size, void* d_ws, size_t ws_size,
                              hipStream_t stream) {
  const float* x   = (const float*)d_in[0];
  const int*   ei  = (const int*)d_in[1];
  const float* w1l = (const float*)d_in[2];
  const float* b1  = (const float*)d_in[3];
  const float* w1r = (const float*)d_in[4];
  const float* w2l = (const float*)d_in[5];
  const float* b2  = (const float*)d_in[6];
  const float* w2r = (const float*)d_in[7];
  float* out = (float*)d_out;

  const int N = in_sizes[0] / IN_DIM;   // 50000
  const int E = in_sizes[1] / 2;        // 800000
  const int* src = ei;
  const int* dst = ei + E;

  // ---- workspace carve ----
  // Region A: AGGb bf16 [N,96] (9.6MB) until gemm1 done; then T2b bf16 [N,64]
  // + R2 f32 [N,64] (19.2MB total).
  char* p = (char*)d_ws;
  uint16_t* AGGb = (uint16_t*)p;
  uint16_t* T2b = (uint16_t*)p;
  float* R2 = (float*)(p + alignUp((size_t)N * 64 * sizeof(uint16_t), 256));
  p += alignUp((size_t)N * 64 * sizeof(uint16_t), 256);
  p += alignUp((size_t)N * 64 * sizeof(float), 256);
  uint16_t* Hb = (uint16_t*)p; p += alignUp((size_t)N * HID * sizeof(uint16_t), 256);
  uint16_t* xb = (uint16_t*)p; p += alignUp((size_t)N * IN_DIM * sizeof(uint16_t), 256);
  uint16_t* S1t = (uint16_t*)p; p += alignUp(128 * 192 * sizeof(uint16_t), 256);
  uint16_t* S2t = (uint16_t*)p; p += alignUp(128 * 128 * sizeof(uint16_t), 256);
  int* deg = (int*)p;    p += alignUp((size_t)N * sizeof(int), 256);
  int* rowptr = (int*)p; p += alignUp((size_t)(N + 1) * sizeof(int), 256);
  int* cursor = (int*)p; p += alignUp((size_t)N * sizeof(int), 256);
  float* inv_deg = (float*)p; p += alignUp((size_t)N * sizeof(float), 256);
  int* adj = (int*)p;    p += alignUp((size_t)E * sizeof(int), 256);
  int* blockSums = (int*)p; p += alignUp(512 * sizeof(int), 256);
  int* blockOffs = (int*)p; p += alignUp(512 * sizeof(int), 256);
  (void)ws_size; (void)n_in; (void)out_size;

  hipMemsetAsync(deg, 0, (size_t)N * sizeof(int), stream);

  const int eBlocks = (E + 255) / 256;
  count_deg_kernel<<<eBlocks, 256, 0, stream>>>(dst, deg, E);

  const int sBlocks = (N + 255) / 256;
  block_sum_kernel<<<sBlocks, 256, 0, stream>>>(deg, blockSums, N);
  scan_blocksums_kernel<<<1, 256, 0, stream>>>(blockSums, blockOffs, rowptr, sBlocks, N);
  write_rowptr_kernel<<<sBlocks, 256, 0, stream>>>(deg, blockOffs, rowptr, cursor, inv_deg, N);

  build_adj_kernel<<<eBlocks, 256, 0, stream>>>(src, dst, cursor, adj, E);

  prep_s_kernel<<<(128 * 192 + 128 * 128 + 255) / 256, 256, 0, stream>>>(w1l, w1r, w2l, w2r, S1t, S2t);
  prep_xb_kernel<<<((N * IN_DIM / 4) + 255) / 256, 256, 0, stream>>>(x, xb, N * IN_DIM / 4);

  const int nodeBlocks = (N + 3) / 4;
  agg1_kernel<<<nodeBlocks, 256, 0, stream>>>(xb, adj, rowptr, inv_deg, AGGb, N);

  const int gemmBlocks = (N + 63) / 64;
  // gemm1: A = [AGGb | xb], K=192 -> Hb (relu + b1)
  gemm_mfma_kernel<<<gemmBlocks, 256, 0, stream>>>(AGGb, xb, IN_DIM, IN_DIM, 192,
                                                   S1t, b1, Hb, nullptr, nullptr, N, 0);
  // gemm2: A = Hb, K=128 -> T2b bf16 + R2 f32 (+b2)
  gemm_mfma_kernel<<<gemmBlocks, 256, 0, stream>>>(Hb, Hb, HID, HID, 128,
                                                   S2t, b2, nullptr, T2b, R2, N, 1);

  final_kernel<<<nodeBlocks, 256, 0, stream>>>(T2b, R2, adj, rowptr, inv_deg, out, N);
}

// Round 5
// 258.531 us; speedup vs baseline: 2.0813x; 1.1584x over previous
//
#include <hip/hip_runtime.h>
#include <cstdint>
#include <cstddef>

// BinSAGE: 2-layer GraphSAGE with sign-binarized weights. MFMA bf16 + bucket-sort CSR.
// N=50000 nodes, E=800000 edges, dims 96 -> 128 -> 64.
//   CSR build: bucket counting sort (196 buckets of 256 nodes):
//     bucket_count -> bucket_scan -> bucket_scatter (packed src|localDst) -> bucket_build
//     All scatters land in dense runs / small L2-hot windows (kills the 16x
//     partial-line writeback amplification of the naive random scatter: 51.8MB -> ~10MB).
//   xb = bf16(x) [N,96]; agg1: mean of xb -> AGGb bf16 [N,96]   (unroll x8)
//   gemm1 (MFMA, no LDS): [AGGb | xb] (K=192) @ S1t^T -> relu -> Hb bf16 [N,128]
//   gemm2 (MFMA, no LDS): Hb (K=128) @ S2t^T -> T2b bf16 [N,64] + R2 f32 [N,64] (+b2)
//   final: out = inv_deg * segsum(T2b[src]) + R2                (unroll x8)

#define N_NODES 50000
#define IN_DIM 96
#define HID 128
#define OUT_DIM 64

typedef __attribute__((ext_vector_type(8))) short bf16x8;
typedef __attribute__((ext_vector_type(4))) float f32x4;

static inline size_t alignUp(size_t v, size_t a) { return (v + a - 1) & ~(a - 1); }

__device__ __forceinline__ uint16_t f2bf(float f) {
  uint32_t u = __float_as_uint(f);
  return (uint16_t)((u + 0x7FFF + ((u >> 16) & 1)) >> 16);
}
__device__ __forceinline__ float bflo(uint32_t v) { return __uint_as_float(v << 16); }
__device__ __forceinline__ float bfhi(uint32_t v) { return __uint_as_float(v & 0xFFFF0000u); }
__device__ __forceinline__ float bf1(uint16_t v) { return __uint_as_float((uint32_t)v << 16); }

// ---------------- CSR build: bucketed counting sort ----------------
// bucket = dst >> 8 (256 nodes/bucket). NB = ceil(N/256) = 196 <= 256.

__global__ __launch_bounds__(256) void bucket_count_kernel(const int* __restrict__ dst,
    int* __restrict__ bucketCnt, int E) {
  __shared__ int h[256];
  const int t = threadIdx.x;
  h[t] = 0;
  __syncthreads();
  const int stride = gridDim.x * 256;
  for (int i = blockIdx.x * 256 + t; i < E; i += stride)
    atomicAdd(&h[dst[i] >> 8], 1);
  __syncthreads();
  if (h[t]) atomicAdd(&bucketCnt[t], h[t]);
}

// 1 block: exclusive scan of NB bucket counts -> bucketBase[0..NB], cursors, rowptr[N]=E.
__global__ __launch_bounds__(256) void bucket_scan_kernel(const int* __restrict__ bucketCnt,
    int* __restrict__ bucketBase, int* __restrict__ bucketCursor, int* __restrict__ rowptr,
    int nB, int N) {
  __shared__ int smem[256];
  const int t = threadIdx.x;
  const int v = (t < nB) ? bucketCnt[t] : 0;
  smem[t] = v;
  __syncthreads();
  for (int off = 1; off < 256; off <<= 1) {
    int u = (t >= off) ? smem[t - off] : 0;
    __syncthreads();
    smem[t] += u;
    __syncthreads();
  }
  if (t < nB) {
    const int excl = smem[t] - v;
    bucketBase[t] = excl;
    bucketCursor[t] = excl;
  }
  if (t == 255) {
    bucketBase[nB] = smem[255];
    rowptr[N] = smem[255];
  }
}

// Per 2048-edge chunk: LDS histogram -> reserve contiguous runs via one global
// atomic per touched bucket -> write packed (src | localDst<<16) densely.
#define SCAT_CHUNK 2048
__global__ __launch_bounds__(256) void bucket_scatter_kernel(const int* __restrict__ src,
    const int* __restrict__ dst, int* __restrict__ bucketCursor,
    uint32_t* __restrict__ bucketBuf, int E) {
  __shared__ int h[256];
  __shared__ int g[256];
  __shared__ int c[256];
  const int t = threadIdx.x;
  const int base = blockIdx.x * SCAT_CHUNK;
  const int end = min(base + SCAT_CHUNK, E);
  h[t] = 0;
  __syncthreads();
  for (int i = base + t; i < end; i += 256)
    atomicAdd(&h[dst[i] >> 8], 1);
  __syncthreads();
  if (h[t]) g[t] = atomicAdd(&bucketCursor[t], h[t]);
  c[t] = 0;
  __syncthreads();
  for (int i = base + t; i < end; i += 256) {
    const int d = dst[i];
    const int b = d >> 8;
    const int ticket = atomicAdd(&c[b], 1);
    bucketBuf[g[b] + ticket] = (uint32_t)src[i] | ((uint32_t)(d & 255) << 16);
  }
}

// One block per bucket: per-node histogram + scan -> rowptr/inv_deg, scatter adj
// within the bucket's contiguous (~16KB, L2-hot) window.
__global__ __launch_bounds__(256) void bucket_build_kernel(const uint32_t* __restrict__ bucketBuf,
    const int* __restrict__ bucketBase, int* __restrict__ rowptr, float* __restrict__ inv_deg,
    int* __restrict__ adj, int N) {
  __shared__ int h[256];
  __shared__ int s[256];
  __shared__ int cur[256];
  const int t = threadIdx.x;
  const int b = blockIdx.x;
  const int nodeBase = b << 8;
  const int beg = bucketBase[b], end = bucketBase[b + 1];
  const int m = end - beg;
  h[t] = 0;
  __syncthreads();
  for (int i = t; i < m; i += 256)
    atomicAdd(&h[(bucketBuf[beg + i] >> 16) & 255], 1);
  __syncthreads();
  const int d = h[t];
  s[t] = d;
  __syncthreads();
  for (int off = 1; off < 256; off <<= 1) {
    int u = (t >= off) ? s[t - off] : 0;
    __syncthreads();
    s[t] += u;
    __syncthreads();
  }
  const int excl = s[t] - d;
  const int node = nodeBase + t;
  if (node < N) {
    rowptr[node] = beg + excl;
    inv_deg[node] = 1.0f / (float)(d > 1 ? d : 1);
  }
  cur[t] = excl;
  __syncthreads();
  for (int i = t; i < m; i += 256) {
    const uint32_t u = bucketBuf[beg + i];
    const int ld = (u >> 16) & 255;
    const int ticket = atomicAdd(&cur[ld], 1);
    adj[beg + ticket] = (int)(u & 0xFFFFu);
  }
}

// ---------------- weights / input prep ----------------

__device__ __forceinline__ uint16_t sgnbf(float w) {
  return (w > 0.f) ? (uint16_t)0x3F80 : ((w < 0.f) ? (uint16_t)0xBF80 : (uint16_t)0);
}

// S1t [128][192] n-major: k<96 -> sgn(w1l[n][k]); k>=96 -> sgn(w1r[n][k-96])
// S2t [128][128] n-major: n<64 -> sgn(w2l[n][k]); n>=64 -> sgn(w2r[n-64][k])
__global__ void prep_s_kernel(const float* __restrict__ w1l, const float* __restrict__ w1r,
                              const float* __restrict__ w2l, const float* __restrict__ w2r,
                              uint16_t* __restrict__ S1t, uint16_t* __restrict__ S2t) {
  int idx = blockIdx.x * blockDim.x + threadIdx.x;
  if (idx < 128 * 192) {
    int n = idx / 192, k = idx - n * 192;
    float w = (k < 96) ? w1l[n * 96 + k] : w1r[n * 96 + (k - 96)];
    S1t[idx] = sgnbf(w);
  } else if (idx < 128 * 192 + 128 * 128) {
    int i2 = idx - 128 * 192;
    int n = i2 >> 7, k = i2 & 127;
    float w = (n < 64) ? w2l[n * 128 + k] : w2r[(n - 64) * 128 + k];
    S2t[i2] = sgnbf(w);
  }
}

__global__ __launch_bounds__(256) void prep_xb_kernel(const float* __restrict__ x,
    uint16_t* __restrict__ xb, int total4) {
  int i = blockIdx.x * blockDim.x + threadIdx.x;
  if (i < total4) {
    float4 v = *(const float4*)(x + (size_t)i * 4);
    uint32_t p0 = (uint32_t)f2bf(v.x) | ((uint32_t)f2bf(v.y) << 16);
    uint32_t p1 = (uint32_t)f2bf(v.z) | ((uint32_t)f2bf(v.w) << 16);
    *(uint2*)(xb + (size_t)i * 4) = make_uint2(p0, p1);
  }
}

// ---------------- gathers ----------------

// One wave per node; lanes 0..47 own feature pairs. Edge loop unrolled x8 for MLP.
__global__ __launch_bounds__(256) void agg1_kernel(const uint16_t* __restrict__ xb,
    const int* __restrict__ adj, const int* __restrict__ rowptr,
    const float* __restrict__ inv_deg, uint16_t* __restrict__ AGGb, int nNodes) {
  const int wave = threadIdx.x >> 6;
  const int lane = threadIdx.x & 63;
  const int n = blockIdx.x * 4 + wave;
  if (n >= nNodes) return;
  const int beg = rowptr[n], end = rowptr[n + 1];
  const bool act = lane < 48;
  const int off = lane * 2;
  float a0 = 0.f, a1 = 0.f;
  int e = beg;
  for (; e + 8 <= end; e += 8) {
    int s[8];
#pragma unroll
    for (int j = 0; j < 8; ++j) s[j] = adj[e + j];
    uint32_t v[8];
#pragma unroll
    for (int j = 0; j < 8; ++j)
      v[j] = act ? *(const uint32_t*)(xb + (size_t)s[j] * IN_DIM + off) : 0u;
#pragma unroll
    for (int j = 0; j < 8; ++j) {
      a0 += bflo(v[j]);
      a1 += bfhi(v[j]);
    }
  }
  for (; e < end; ++e) {
    const int sj = adj[e];
    uint32_t v = act ? *(const uint32_t*)(xb + (size_t)sj * IN_DIM + off) : 0u;
    a0 += bflo(v);
    a1 += bfhi(v);
  }
  if (act) {
    const float inv = inv_deg[n];
    uint32_t pk = (uint32_t)f2bf(a0 * inv) | ((uint32_t)f2bf(a1 * inv) << 16);
    *(uint32_t*)(AGGb + (size_t)n * IN_DIM + off) = pk;
  }
}

// out[n][c] = inv_deg[n] * sum_e bf16(T2b[src_e][c]) + R2[n][c]; lane=c. Unroll x8.
__global__ __launch_bounds__(256) void final_kernel(const uint16_t* __restrict__ T2b,
    const float* __restrict__ R2, const int* __restrict__ adj, const int* __restrict__ rowptr,
    const float* __restrict__ inv_deg, float* __restrict__ out, int nNodes) {
  const int wave = threadIdx.x >> 6;
  const int lane = threadIdx.x & 63;
  const int n = blockIdx.x * 4 + wave;
  if (n >= nNodes) return;
  const int beg = rowptr[n], end = rowptr[n + 1];
  float acc = 0.f;
  int e = beg;
  for (; e + 8 <= end; e += 8) {
    int s[8];
#pragma unroll
    for (int j = 0; j < 8; ++j) s[j] = adj[e + j];
    float f[8];
#pragma unroll
    for (int j = 0; j < 8; ++j) f[j] = bf1(T2b[(size_t)s[j] * 64 + lane]);
#pragma unroll
    for (int j = 0; j < 8; ++j) acc += f[j];
  }
  for (; e < end; ++e) acc += bf1(T2b[(size_t)adj[e] * 64 + lane]);
  out[(size_t)n * 64 + lane] = acc * inv_deg[n] + R2[(size_t)n * 64 + lane];
}

// ---------------- MFMA GEMM (no LDS) ----------------
// Block = 4 waves = 64 rows; wave = 16 rows x 128 cols.
__global__ __launch_bounds__(256) void gemm_mfma_kernel(
    const uint16_t* __restrict__ Aa, const uint16_t* __restrict__ Ab,
    int lda, int split, int K,
    const uint16_t* __restrict__ Bt, const float* __restrict__ bias,
    uint16_t* __restrict__ Hb, uint16_t* __restrict__ T2b, float* __restrict__ R2,
    int M, int mode) {
  const int tid = threadIdx.x;
  const int wv = tid >> 6;
  const int lane = tid & 63;
  const int m16 = lane & 15;
  const int quad = lane >> 4;
  const int rowBase = blockIdx.x * 64 + wv * 16;
  int arow = rowBase + m16;
  if (arow >= M) arow = M - 1;  // clamp; stores are guarded

  f32x4 acc[8];
#pragma unroll
  for (int cf = 0; cf < 8; ++cf) acc[cf] = (f32x4){0.f, 0.f, 0.f, 0.f};

  const int kq = quad * 8;
  for (int k0 = 0; k0 < K; k0 += 32) {
    const int k = k0 + kq;
    const uint16_t* ap = (k < split) ? (Aa + (size_t)arow * lda + k)
                                     : (Ab + (size_t)arow * lda + (k - split));
    const bf16x8 a = *(const bf16x8*)ap;
    bf16x8 b[8];
#pragma unroll
    for (int cf = 0; cf < 8; ++cf)
      b[cf] = *(const bf16x8*)(Bt + (size_t)(cf * 16 + m16) * K + k);
#pragma unroll
    for (int cf = 0; cf < 8; ++cf)
      acc[cf] = __builtin_amdgcn_mfma_f32_16x16x32_bf16(a, b[cf], acc[cf], 0, 0, 0);
  }

#pragma unroll
  for (int cf = 0; cf < 8; ++cf) {
    const int col = cf * 16 + m16;
#pragma unroll
    for (int r = 0; r < 4; ++r) {
      const int row = rowBase + quad * 4 + r;
      if (row < M) {
        float v = acc[cf][r];
        if (mode == 0) {
          v = fmaxf(v + bias[col], 0.f);
          Hb[(size_t)row * 128 + col] = f2bf(v);
        } else if (col < 64) {
          T2b[(size_t)row * 64 + col] = f2bf(v);
        } else {
          R2[(size_t)row * 64 + (col - 64)] = v + bias[col - 64];
        }
      }
    }
  }
}

extern "C" void kernel_launch(void* const* d_in, const int* in_sizes, int n_in,
                              void* d_out, int out_size, void* d_ws, size_t ws_size,
                              hipStream_t stream) {
  const float* x   = (const float*)d_in[0];
  const int*   ei  = (const int*)d_in[1];
  const float* w1l = (const float*)d_in[2];
  const float* b1  = (const float*)d_in[3];
  const float* w1r = (const float*)d_in[4];
  const float* w2l = (const float*)d_in[5];
  const float* b2  = (const float*)d_in[6];
  const float* w2r = (const float*)d_in[7];
  float* out = (float*)d_out;

  const int N = in_sizes[0] / IN_DIM;   // 50000
  const int E = in_sizes[1] / 2;        // 800000
  const int* src = ei;
  const int* dst = ei + E;
  const int NB = (N + 255) >> 8;        // 196 buckets

  // ---- workspace carve ----
  char* p = (char*)d_ws;
  uint16_t* AGGb = (uint16_t*)p;        // [N,96] bf16, reused as T2b+R2 after gemm1
  uint16_t* T2b = (uint16_t*)p;
  float* R2 = (float*)(p + alignUp((size_t)N * 64 * sizeof(uint16_t), 256));
  p += alignUp((size_t)N * 64 * sizeof(uint16_t), 256);
  p += alignUp((size_t)N * 64 * sizeof(float), 256);
  uint16_t* Hb = (uint16_t*)p; p += alignUp((size_t)N * HID * sizeof(uint16_t), 256);
  uint16_t* xb = (uint16_t*)p; p += alignUp((size_t)N * IN_DIM * sizeof(uint16_t), 256);
  uint16_t* S1t = (uint16_t*)p; p += alignUp(128 * 192 * sizeof(uint16_t), 256);
  uint16_t* S2t = (uint16_t*)p; p += alignUp(128 * 128 * sizeof(uint16_t), 256);
  int* rowptr = (int*)p; p += alignUp((size_t)(N + 1) * sizeof(int), 256);
  float* inv_deg = (float*)p; p += alignUp((size_t)N * sizeof(float), 256);
  int* adj = (int*)p;    p += alignUp((size_t)E * sizeof(int), 256);
  uint32_t* bucketBuf = (uint32_t*)p; p += alignUp((size_t)E * sizeof(uint32_t), 256);
  int* bucketCnt = (int*)p;    p += alignUp(256 * sizeof(int), 256);
  int* bucketBase = (int*)p;   p += alignUp(257 * sizeof(int), 256);
  int* bucketCursor = (int*)p; p += alignUp(256 * sizeof(int), 256);
  (void)ws_size; (void)n_in; (void)out_size;

  hipMemsetAsync(bucketCnt, 0, 256 * sizeof(int), stream);

  // CSR build via bucket counting sort
  bucket_count_kernel<<<256, 256, 0, stream>>>(dst, bucketCnt, E);
  bucket_scan_kernel<<<1, 256, 0, stream>>>(bucketCnt, bucketBase, bucketCursor, rowptr, NB, N);
  bucket_scatter_kernel<<<(E + SCAT_CHUNK - 1) / SCAT_CHUNK, 256, 0, stream>>>(
      src, dst, bucketCursor, bucketBuf, E);
  bucket_build_kernel<<<NB, 256, 0, stream>>>(bucketBuf, bucketBase, rowptr, inv_deg, adj, N);

  prep_s_kernel<<<(128 * 192 + 128 * 128 + 255) / 256, 256, 0, stream>>>(w1l, w1r, w2l, w2r, S1t, S2t);
  prep_xb_kernel<<<((N * IN_DIM / 4) + 255) / 256, 256, 0, stream>>>(x, xb, N * IN_DIM / 4);

  const int nodeBlocks = (N + 3) / 4;
  agg1_kernel<<<nodeBlocks, 256, 0, stream>>>(xb, adj, rowptr, inv_deg, AGGb, N);

  const int gemmBlocks = (N + 63) / 64;
  gemm_mfma_kernel<<<gemmBlocks, 256, 0, stream>>>(AGGb, xb, IN_DIM, IN_DIM, 192,
                                                   S1t, b1, Hb, nullptr, nullptr, N, 0);
  gemm_mfma_kernel<<<gemmBlocks, 256, 0, stream>>>(Hb, Hb, HID, HID, 128,
                                                   S2t, b2, nullptr, T2b, R2, N, 1);

  final_kernel<<<nodeBlocks, 256, 0, stream>>>(T2b, R2, adj, rowptr, inv_deg, out, N);
}

// Round 6
// 237.449 us; speedup vs baseline: 2.2661x; 1.0888x over previous
//
#include <hip/hip_runtime.h>
#include <cstdint>
#include <cstddef>

// BinSAGE: 2-layer GraphSAGE with sign-binarized weights. MFMA bf16 + bucket-sort CSR.
// N=50000 nodes, E=800000 edges, dims 96 -> 128 -> 64.
//   CSR build: bucket counting sort (196 buckets of 256 nodes).
//   xb = bf16(x) [N,96]; agg1: mean of xb -> AGGb bf16 [N,96]
//   gemm1 (MFMA, no LDS): [AGGb | xb] (K=192) @ S1t^T -> relu -> Hb bf16 [N,128]
//   gemm2 (MFMA, no LDS): Hb (K=128) @ S2t^T -> T2b bf16 [N,64] + R2 f32 [N,64] (+b2)
//   final: out = inv_deg * segsum(T2b[src]) + R2
// Gather kernels: one wave per node, adj indices loaded ONCE into a register
// (64/lane-wide load) and broadcast via __shfl; the wave's two 32-lane halves
// gather two different edges per instruction (16 edges in flight at unroll 8),
// halves combined at the end with __shfl_xor(32). ~1 memory round-trip/node.

#define N_NODES 50000
#define IN_DIM 96
#define HID 128
#define OUT_DIM 64

typedef __attribute__((ext_vector_type(8))) short bf16x8;
typedef __attribute__((ext_vector_type(4))) float f32x4;

static inline size_t alignUp(size_t v, size_t a) { return (v + a - 1) & ~(a - 1); }

__device__ __forceinline__ uint16_t f2bf(float f) {
  uint32_t u = __float_as_uint(f);
  return (uint16_t)((u + 0x7FFF + ((u >> 16) & 1)) >> 16);
}
__device__ __forceinline__ float bflo(uint32_t v) { return __uint_as_float(v << 16); }
__device__ __forceinline__ float bfhi(uint32_t v) { return __uint_as_float(v & 0xFFFF0000u); }

// ---------------- CSR build: bucketed counting sort ----------------
__global__ __launch_bounds__(256) void bucket_count_kernel(const int* __restrict__ dst,
    int* __restrict__ bucketCnt, int E) {
  __shared__ int h[256];
  const int t = threadIdx.x;
  h[t] = 0;
  __syncthreads();
  const int stride = gridDim.x * 256;
  for (int i = blockIdx.x * 256 + t; i < E; i += stride)
    atomicAdd(&h[dst[i] >> 8], 1);
  __syncthreads();
  if (h[t]) atomicAdd(&bucketCnt[t], h[t]);
}

__global__ __launch_bounds__(256) void bucket_scan_kernel(const int* __restrict__ bucketCnt,
    int* __restrict__ bucketBase, int* __restrict__ bucketCursor, int* __restrict__ rowptr,
    int nB, int N) {
  __shared__ int smem[256];
  const int t = threadIdx.x;
  const int v = (t < nB) ? bucketCnt[t] : 0;
  smem[t] = v;
  __syncthreads();
  for (int off = 1; off < 256; off <<= 1) {
    int u = (t >= off) ? smem[t - off] : 0;
    __syncthreads();
    smem[t] += u;
    __syncthreads();
  }
  if (t < nB) {
    const int excl = smem[t] - v;
    bucketBase[t] = excl;
    bucketCursor[t] = excl;
  }
  if (t == 255) {
    bucketBase[nB] = smem[255];
    rowptr[N] = smem[255];
  }
}

#define SCAT_CHUNK 2048
__global__ __launch_bounds__(256) void bucket_scatter_kernel(const int* __restrict__ src,
    const int* __restrict__ dst, int* __restrict__ bucketCursor,
    uint32_t* __restrict__ bucketBuf, int E) {
  __shared__ int h[256];
  __shared__ int g[256];
  __shared__ int c[256];
  const int t = threadIdx.x;
  const int base = blockIdx.x * SCAT_CHUNK;
  const int end = min(base + SCAT_CHUNK, E);
  h[t] = 0;
  __syncthreads();
  for (int i = base + t; i < end; i += 256)
    atomicAdd(&h[dst[i] >> 8], 1);
  __syncthreads();
  if (h[t]) g[t] = atomicAdd(&bucketCursor[t], h[t]);
  c[t] = 0;
  __syncthreads();
  for (int i = base + t; i < end; i += 256) {
    const int d = dst[i];
    const int b = d >> 8;
    const int ticket = atomicAdd(&c[b], 1);
    bucketBuf[g[b] + ticket] = (uint32_t)src[i] | ((uint32_t)(d & 255) << 16);
  }
}

__global__ __launch_bounds__(256) void bucket_build_kernel(const uint32_t* __restrict__ bucketBuf,
    const int* __restrict__ bucketBase, int* __restrict__ rowptr, float* __restrict__ inv_deg,
    int* __restrict__ adj, int N) {
  __shared__ int h[256];
  __shared__ int s[256];
  __shared__ int cur[256];
  const int t = threadIdx.x;
  const int b = blockIdx.x;
  const int nodeBase = b << 8;
  const int beg = bucketBase[b], end = bucketBase[b + 1];
  const int m = end - beg;
  h[t] = 0;
  __syncthreads();
  for (int i = t; i < m; i += 256)
    atomicAdd(&h[(bucketBuf[beg + i] >> 16) & 255], 1);
  __syncthreads();
  const int d = h[t];
  s[t] = d;
  __syncthreads();
  for (int off = 1; off < 256; off <<= 1) {
    int u = (t >= off) ? s[t - off] : 0;
    __syncthreads();
    s[t] += u;
    __syncthreads();
  }
  const int excl = s[t] - d;
  const int node = nodeBase + t;
  if (node < N) {
    rowptr[node] = beg + excl;
    inv_deg[node] = 1.0f / (float)(d > 1 ? d : 1);
  }
  cur[t] = excl;
  __syncthreads();
  for (int i = t; i < m; i += 256) {
    const uint32_t u = bucketBuf[beg + i];
    const int ld = (u >> 16) & 255;
    const int ticket = atomicAdd(&cur[ld], 1);
    adj[beg + ticket] = (int)(u & 0xFFFFu);
  }
}

// ---------------- weights / input prep ----------------
__device__ __forceinline__ uint16_t sgnbf(float w) {
  return (w > 0.f) ? (uint16_t)0x3F80 : ((w < 0.f) ? (uint16_t)0xBF80 : (uint16_t)0);
}

__global__ void prep_s_kernel(const float* __restrict__ w1l, const float* __restrict__ w1r,
                              const float* __restrict__ w2l, const float* __restrict__ w2r,
                              uint16_t* __restrict__ S1t, uint16_t* __restrict__ S2t) {
  int idx = blockIdx.x * blockDim.x + threadIdx.x;
  if (idx < 128 * 192) {
    int n = idx / 192, k = idx - n * 192;
    float w = (k < 96) ? w1l[n * 96 + k] : w1r[n * 96 + (k - 96)];
    S1t[idx] = sgnbf(w);
  } else if (idx < 128 * 192 + 128 * 128) {
    int i2 = idx - 128 * 192;
    int n = i2 >> 7, k = i2 & 127;
    float w = (n < 64) ? w2l[n * 128 + k] : w2r[(n - 64) * 128 + k];
    S2t[i2] = sgnbf(w);
  }
}

__global__ __launch_bounds__(256) void prep_xb_kernel(const float* __restrict__ x,
    uint16_t* __restrict__ xb, int total4) {
  int i = blockIdx.x * blockDim.x + threadIdx.x;
  if (i < total4) {
    float4 v = *(const float4*)(x + (size_t)i * 4);
    uint32_t p0 = (uint32_t)f2bf(v.x) | ((uint32_t)f2bf(v.y) << 16);
    uint32_t p1 = (uint32_t)f2bf(v.z) | ((uint32_t)f2bf(v.w) << 16);
    *(uint2*)(xb + (size_t)i * 4) = make_uint2(p0, p1);
  }
}

// ---------------- gathers ----------------

// Wave per node. Half-wave p in {0,1} gathers edge 2*it+p; lane j=lane&31 (<24
// active) covers features 4j..4j+3 (uint2 = 8B). adj held in a register
// (64/wave-wide load), broadcast by __shfl. 16 edges in flight at unroll 8.
__global__ __launch_bounds__(256) void agg1_kernel(const uint16_t* __restrict__ xb,
    const int* __restrict__ adj, const int* __restrict__ rowptr,
    const float* __restrict__ inv_deg, uint16_t* __restrict__ AGGb, int nNodes) {
  const int wave = threadIdx.x >> 6;
  const int lane = threadIdx.x & 63;
  const int n = blockIdx.x * 4 + wave;
  if (n >= nNodes) return;
  const int beg = rowptr[n], end = rowptr[n + 1];
  const int p = lane >> 5;
  const int j = lane & 31;
  const bool act = j < 24;
  const int foff = j * 4;
  float a0 = 0.f, a1 = 0.f, a2 = 0.f, a3 = 0.f;

  for (int bb = beg; bb < end; bb += 64) {
    const int cnt = min(64, end - bb);
    const int adjv = (lane < cnt) ? adj[bb + lane] : 0;
    const int pairs = (cnt + 1) >> 1;
    int it = 0;
    for (; it + 8 <= pairs; it += 8) {
#pragma unroll
      for (int u = 0; u < 8; ++u) {
        const int e = 2 * (it + u) + p;
        const int s = __shfl(adjv, e);
        uint2 v = make_uint2(0u, 0u);
        if (act && e < cnt) v = *(const uint2*)(xb + (size_t)s * IN_DIM + foff);
        a0 += bflo(v.x); a1 += bfhi(v.x);
        a2 += bflo(v.y); a3 += bfhi(v.y);
      }
    }
    for (; it < pairs; ++it) {
      const int e = 2 * it + p;
      const int s = __shfl(adjv, e);
      uint2 v = make_uint2(0u, 0u);
      if (act && e < cnt) v = *(const uint2*)(xb + (size_t)s * IN_DIM + foff);
      a0 += bflo(v.x); a1 += bfhi(v.x);
      a2 += bflo(v.y); a3 += bfhi(v.y);
    }
  }
  a0 += __shfl_xor(a0, 32);
  a1 += __shfl_xor(a1, 32);
  a2 += __shfl_xor(a2, 32);
  a3 += __shfl_xor(a3, 32);
  if (p == 0 && act) {
    const float inv = inv_deg[n];
    uint2 o;
    o.x = (uint32_t)f2bf(a0 * inv) | ((uint32_t)f2bf(a1 * inv) << 16);
    o.y = (uint32_t)f2bf(a2 * inv) | ((uint32_t)f2bf(a3 * inv) << 16);
    *(uint2*)(AGGb + (size_t)n * IN_DIM + foff) = o;
  }
}

// Same structure; T2b rows are 64 bf16 = 128B: lane j covers features 2j,2j+1.
__global__ __launch_bounds__(256) void final_kernel(const uint16_t* __restrict__ T2b,
    const float* __restrict__ R2, const int* __restrict__ adj, const int* __restrict__ rowptr,
    const float* __restrict__ inv_deg, float* __restrict__ out, int nNodes) {
  const int wave = threadIdx.x >> 6;
  const int lane = threadIdx.x & 63;
  const int n = blockIdx.x * 4 + wave;
  if (n >= nNodes) return;
  const int beg = rowptr[n], end = rowptr[n + 1];
  const int p = lane >> 5;
  const int j = lane & 31;
  float a0 = 0.f, a1 = 0.f;

  for (int bb = beg; bb < end; bb += 64) {
    const int cnt = min(64, end - bb);
    const int adjv = (lane < cnt) ? adj[bb + lane] : 0;
    const int pairs = (cnt + 1) >> 1;
    int it = 0;
    for (; it + 8 <= pairs; it += 8) {
#pragma unroll
      for (int u = 0; u < 8; ++u) {
        const int e = 2 * (it + u) + p;
        const int s = __shfl(adjv, e);
        uint32_t v = 0u;
        if (e < cnt) v = *(const uint32_t*)(T2b + (size_t)s * 64 + j * 2);
        a0 += bflo(v); a1 += bfhi(v);
      }
    }
    for (; it < pairs; ++it) {
      const int e = 2 * it + p;
      const int s = __shfl(adjv, e);
      uint32_t v = 0u;
      if (e < cnt) v = *(const uint32_t*)(T2b + (size_t)s * 64 + j * 2);
      a0 += bflo(v); a1 += bfhi(v);
    }
  }
  a0 += __shfl_xor(a0, 32);
  a1 += __shfl_xor(a1, 32);
  if (p == 0) {
    const float inv = inv_deg[n];
    const float2 r = *(const float2*)(R2 + (size_t)n * 64 + j * 2);
    float2 o;
    o.x = a0 * inv + r.x;
    o.y = a1 * inv + r.y;
    *(float2*)(out + (size_t)n * 64 + j * 2) = o;
  }
}

// ---------------- MFMA GEMM (no LDS) ----------------
__global__ __launch_bounds__(256) void gemm_mfma_kernel(
    const uint16_t* __restrict__ Aa, const uint16_t* __restrict__ Ab,
    int lda, int split, int K,
    const uint16_t* __restrict__ Bt, const float* __restrict__ bias,
    uint16_t* __restrict__ Hb, uint16_t* __restrict__ T2b, float* __restrict__ R2,
    int M, int mode) {
  const int tid = threadIdx.x;
  const int wv = tid >> 6;
  const int lane = tid & 63;
  const int m16 = lane & 15;
  const int quad = lane >> 4;
  const int rowBase = blockIdx.x * 64 + wv * 16;
  int arow = rowBase + m16;
  if (arow >= M) arow = M - 1;  // clamp; stores are guarded

  f32x4 acc[8];
#pragma unroll
  for (int cf = 0; cf < 8; ++cf) acc[cf] = (f32x4){0.f, 0.f, 0.f, 0.f};

  const int kq = quad * 8;
  for (int k0 = 0; k0 < K; k0 += 32) {
    const int k = k0 + kq;
    const uint16_t* ap = (k < split) ? (Aa + (size_t)arow * lda + k)
                                     : (Ab + (size_t)arow * lda + (k - split));
    const bf16x8 a = *(const bf16x8*)ap;
    bf16x8 b[8];
#pragma unroll
    for (int cf = 0; cf < 8; ++cf)
      b[cf] = *(const bf16x8*)(Bt + (size_t)(cf * 16 + m16) * K + k);
#pragma unroll
    for (int cf = 0; cf < 8; ++cf)
      acc[cf] = __builtin_amdgcn_mfma_f32_16x16x32_bf16(a, b[cf], acc[cf], 0, 0, 0);
  }

#pragma unroll
  for (int cf = 0; cf < 8; ++cf) {
    const int col = cf * 16 + m16;
#pragma unroll
    for (int r = 0; r < 4; ++r) {
      const int row = rowBase + quad * 4 + r;
      if (row < M) {
        float v = acc[cf][r];
        if (mode == 0) {
          v = fmaxf(v + bias[col], 0.f);
          Hb[(size_t)row * 128 + col] = f2bf(v);
        } else if (col < 64) {
          T2b[(size_t)row * 64 + col] = f2bf(v);
        } else {
          R2[(size_t)row * 64 + (col - 64)] = v + bias[col - 64];
        }
      }
    }
  }
}

extern "C" void kernel_launch(void* const* d_in, const int* in_sizes, int n_in,
                              void* d_out, int out_size, void* d_ws, size_t ws_size,
                              hipStream_t stream) {
  const float* x   = (const float*)d_in[0];
  const int*   ei  = (const int*)d_in[1];
  const float* w1l = (const float*)d_in[2];
  const float* b1  = (const float*)d_in[3];
  const float* w1r = (const float*)d_in[4];
  const float* w2l = (const float*)d_in[5];
  const float* b2  = (const float*)d_in[6];
  const float* w2r = (const float*)d_in[7];
  float* out = (float*)d_out;

  const int N = in_sizes[0] / IN_DIM;   // 50000
  const int E = in_sizes[1] / 2;        // 800000
  const int* src = ei;
  const int* dst = ei + E;
  const int NB = (N + 255) >> 8;        // 196 buckets

  // ---- workspace carve ----
  char* p = (char*)d_ws;
  uint16_t* AGGb = (uint16_t*)p;        // [N,96] bf16, reused as T2b+R2 after gemm1
  uint16_t* T2b = (uint16_t*)p;
  float* R2 = (float*)(p + alignUp((size_t)N * 64 * sizeof(uint16_t), 256));
  p += alignUp((size_t)N * 64 * sizeof(uint16_t), 256);
  p += alignUp((size_t)N * 64 * sizeof(float), 256);
  uint16_t* Hb = (uint16_t*)p; p += alignUp((size_t)N * HID * sizeof(uint16_t), 256);
  uint16_t* xb = (uint16_t*)p; p += alignUp((size_t)N * IN_DIM * sizeof(uint16_t), 256);
  uint16_t* S1t = (uint16_t*)p; p += alignUp(128 * 192 * sizeof(uint16_t), 256);
  uint16_t* S2t = (uint16_t*)p; p += alignUp(128 * 128 * sizeof(uint16_t), 256);
  int* rowptr = (int*)p; p += alignUp((size_t)(N + 1) * sizeof(int), 256);
  float* inv_deg = (float*)p; p += alignUp((size_t)N * sizeof(float), 256);
  int* adj = (int*)p;    p += alignUp((size_t)E * sizeof(int), 256);
  uint32_t* bucketBuf = (uint32_t*)p; p += alignUp((size_t)E * sizeof(uint32_t), 256);
  int* bucketCnt = (int*)p;    p += alignUp(256 * sizeof(int), 256);
  int* bucketBase = (int*)p;   p += alignUp(257 * sizeof(int), 256);
  int* bucketCursor = (int*)p; p += alignUp(256 * sizeof(int), 256);
  (void)ws_size; (void)n_in; (void)out_size;

  hipMemsetAsync(bucketCnt, 0, 256 * sizeof(int), stream);

  bucket_count_kernel<<<256, 256, 0, stream>>>(dst, bucketCnt, E);
  bucket_scan_kernel<<<1, 256, 0, stream>>>(bucketCnt, bucketBase, bucketCursor, rowptr, NB, N);
  bucket_scatter_kernel<<<(E + SCAT_CHUNK - 1) / SCAT_CHUNK, 256, 0, stream>>>(
      src, dst, bucketCursor, bucketBuf, E);
  bucket_build_kernel<<<NB, 256, 0, stream>>>(bucketBuf, bucketBase, rowptr, inv_deg, adj, N);

  prep_s_kernel<<<(128 * 192 + 128 * 128 + 255) / 256, 256, 0, stream>>>(w1l, w1r, w2l, w2r, S1t, S2t);
  prep_xb_kernel<<<((N * IN_DIM / 4) + 255) / 256, 256, 0, stream>>>(x, xb, N * IN_DIM / 4);

  const int nodeBlocks = (N + 3) / 4;
  agg1_kernel<<<nodeBlocks, 256, 0, stream>>>(xb, adj, rowptr, inv_deg, AGGb, N);

  const int gemmBlocks = (N + 63) / 64;
  gemm_mfma_kernel<<<gemmBlocks, 256, 0, stream>>>(AGGb, xb, IN_DIM, IN_DIM, 192,
                                                   S1t, b1, Hb, nullptr, nullptr, N, 0);
  gemm_mfma_kernel<<<gemmBlocks, 256, 0, stream>>>(Hb, Hb, HID, HID, 128,
                                                   S2t, b2, nullptr, T2b, R2, N, 1);

  final_kernel<<<nodeBlocks, 256, 0, stream>>>(T2b, R2, adj, rowptr, inv_deg, out, N);
}

// Round 8
// 218.089 us; speedup vs baseline: 2.4673x; 1.0888x over previous
//
#include <hip/hip_runtime.h>
#include <cstdint>
#include <cstddef>

// BinSAGE: 2-layer GraphSAGE with sign-binarized weights. MFMA bf16 + bucket-sort CSR.
// N=50000 nodes, E=800000 edges, dims 96 -> 128 -> 64.
//   CSR build: bucket counting sort (196 buckets of 256 nodes), adj stored u16.
//   prep (1 dispatch): S1t/S2t sign matrices bf16 + xb = bf16(x)
//   agg1: mean of xb over in-edges -> AGGb bf16 [N,96]  (4 edges/instr, uint4)
//   gemm12 (fused, MFMA, LDS H-tile): [AGGb|xb] @ S1t^T -> relu -> H (LDS bf16)
//                                     H @ S2t^T -> T2b bf16 [N,64] + R2 f32 [N,64]
//   final: out = inv_deg * segsum(T2b[src]) + R2     (4 edges/instr, uint2)
// NOTE (round-7 bug): AGGb must NOT alias T2b/R2 — the fused gemm12 reads AGGb
// while writing T2b/R2 across concurrent blocks. AGGb now has its own region.

#define N_NODES 50000
#define IN_DIM 96
#define HID 128
#define OUT_DIM 64

typedef __attribute__((ext_vector_type(8))) short bf16x8;
typedef __attribute__((ext_vector_type(4))) float f32x4;

static inline size_t alignUp(size_t v, size_t a) { return (v + a - 1) & ~(a - 1); }

__device__ __forceinline__ uint16_t f2bf(float f) {
  uint32_t u = __float_as_uint(f);
  return (uint16_t)((u + 0x7FFF + ((u >> 16) & 1)) >> 16);
}
__device__ __forceinline__ float bflo(uint32_t v) { return __uint_as_float(v << 16); }
__device__ __forceinline__ float bfhi(uint32_t v) { return __uint_as_float(v & 0xFFFF0000u); }

// ---------------- CSR build: bucketed counting sort ----------------
__global__ __launch_bounds__(256) void bucket_count_kernel(const int* __restrict__ dst,
    int* __restrict__ bucketCnt, int E) {
  __shared__ int h[256];
  const int t = threadIdx.x;
  h[t] = 0;
  __syncthreads();
  const int stride = gridDim.x * 256;
  for (int i = blockIdx.x * 256 + t; i < E; i += stride)
    atomicAdd(&h[dst[i] >> 8], 1);
  __syncthreads();
  if (h[t]) atomicAdd(&bucketCnt[t], h[t]);
}

__global__ __launch_bounds__(256) void bucket_scan_kernel(const int* __restrict__ bucketCnt,
    int* __restrict__ bucketBase, int* __restrict__ bucketCursor, int* __restrict__ rowptr,
    int nB, int N) {
  __shared__ int smem[256];
  const int t = threadIdx.x;
  const int v = (t < nB) ? bucketCnt[t] : 0;
  smem[t] = v;
  __syncthreads();
  for (int off = 1; off < 256; off <<= 1) {
    int u = (t >= off) ? smem[t - off] : 0;
    __syncthreads();
    smem[t] += u;
    __syncthreads();
  }
  if (t < nB) {
    const int excl = smem[t] - v;
    bucketBase[t] = excl;
    bucketCursor[t] = excl;
  }
  if (t == 255) {
    bucketBase[nB] = smem[255];
    rowptr[N] = smem[255];
  }
}

#define SCAT_CHUNK 2048
__global__ __launch_bounds__(256) void bucket_scatter_kernel(const int* __restrict__ src,
    const int* __restrict__ dst, int* __restrict__ bucketCursor,
    uint32_t* __restrict__ bucketBuf, int E) {
  __shared__ int h[256];
  __shared__ int g[256];
  __shared__ int c[256];
  const int t = threadIdx.x;
  const int base = blockIdx.x * SCAT_CHUNK;
  const int end = min(base + SCAT_CHUNK, E);
  h[t] = 0;
  __syncthreads();
  for (int i = base + t; i < end; i += 256)
    atomicAdd(&h[dst[i] >> 8], 1);
  __syncthreads();
  if (h[t]) g[t] = atomicAdd(&bucketCursor[t], h[t]);
  c[t] = 0;
  __syncthreads();
  for (int i = base + t; i < end; i += 256) {
    const int d = dst[i];
    const int b = d >> 8;
    const int ticket = atomicAdd(&c[b], 1);
    bucketBuf[g[b] + ticket] = (uint32_t)src[i] | ((uint32_t)(d & 255) << 16);
  }
}

__global__ __launch_bounds__(256) void bucket_build_kernel(const uint32_t* __restrict__ bucketBuf,
    const int* __restrict__ bucketBase, int* __restrict__ rowptr, float* __restrict__ inv_deg,
    uint16_t* __restrict__ adj16, int N) {
  __shared__ int h[256];
  __shared__ int s[256];
  __shared__ int cur[256];
  const int t = threadIdx.x;
  const int b = blockIdx.x;
  const int nodeBase = b << 8;
  const int beg = bucketBase[b], end = bucketBase[b + 1];
  const int m = end - beg;
  h[t] = 0;
  __syncthreads();
  for (int i = t; i < m; i += 256)
    atomicAdd(&h[(bucketBuf[beg + i] >> 16) & 255], 1);
  __syncthreads();
  const int d = h[t];
  s[t] = d;
  __syncthreads();
  for (int off = 1; off < 256; off <<= 1) {
    int u = (t >= off) ? s[t - off] : 0;
    __syncthreads();
    s[t] += u;
    __syncthreads();
  }
  const int excl = s[t] - d;
  const int node = nodeBase + t;
  if (node < N) {
    rowptr[node] = beg + excl;
    inv_deg[node] = 1.0f / (float)(d > 1 ? d : 1);
  }
  cur[t] = excl;
  __syncthreads();
  for (int i = t; i < m; i += 256) {
    const uint32_t u = bucketBuf[beg + i];
    const int ld = (u >> 16) & 255;
    const int ticket = atomicAdd(&cur[ld], 1);
    adj16[beg + ticket] = (uint16_t)(u & 0xFFFFu);
  }
}

// ---------------- combined prep: sign matrices + x->bf16 ----------------
__device__ __forceinline__ uint16_t sgnbf(float w) {
  return (w > 0.f) ? (uint16_t)0x3F80 : ((w < 0.f) ? (uint16_t)0xBF80 : (uint16_t)0);
}

#define NS1 (128 * 192)
#define NS2 (128 * 128)
__global__ __launch_bounds__(256) void prep_kernel(const float* __restrict__ x,
    const float* __restrict__ w1l, const float* __restrict__ w1r,
    const float* __restrict__ w2l, const float* __restrict__ w2r,
    uint16_t* __restrict__ S1t, uint16_t* __restrict__ S2t,
    uint16_t* __restrict__ xb, int total4) {
  int idx = blockIdx.x * blockDim.x + threadIdx.x;
  if (idx < NS1) {
    int n = idx / 192, k = idx - n * 192;
    float w = (k < 96) ? w1l[n * 96 + k] : w1r[n * 96 + (k - 96)];
    S1t[idx] = sgnbf(w);
  } else if (idx < NS1 + NS2) {
    int i2 = idx - NS1;
    int n = i2 >> 7, k = i2 & 127;
    float w = (n < 64) ? w2l[n * 128 + k] : w2r[(n - 64) * 128 + k];
    S2t[i2] = sgnbf(w);
  } else {
    int i = idx - NS1 - NS2;
    if (i < total4) {
      float4 v = *(const float4*)(x + (size_t)i * 4);
      uint32_t p0 = (uint32_t)f2bf(v.x) | ((uint32_t)f2bf(v.y) << 16);
      uint32_t p1 = (uint32_t)f2bf(v.z) | ((uint32_t)f2bf(v.w) << 16);
      *(uint2*)(xb + (size_t)i * 4) = make_uint2(p0, p1);
    }
  }
}

// ---------------- gathers ----------------
// Wave per node; 4 subgroups of 16 lanes each gather a different edge.
__global__ __launch_bounds__(256) void agg1_kernel(const uint16_t* __restrict__ xb,
    const uint16_t* __restrict__ adj16, const int* __restrict__ rowptr,
    const float* __restrict__ inv_deg, uint16_t* __restrict__ AGGb, int nNodes) {
  const int wave = threadIdx.x >> 6;
  const int lane = threadIdx.x & 63;
  const int n = blockIdx.x * 4 + wave;
  if (n >= nNodes) return;
  const int beg = rowptr[n], end = rowptr[n + 1];
  const int g = lane >> 4;
  const int j = lane & 15;
  const bool act = j < 12;
  const int foff = j * 8;  // features 8j..8j+7
  float a0 = 0.f, a1 = 0.f, a2 = 0.f, a3 = 0.f, a4 = 0.f, a5 = 0.f, a6 = 0.f, a7 = 0.f;

  for (int bb = beg; bb < end; bb += 64) {
    const int cnt = min(64, end - bb);
    const int adjv = (lane < cnt) ? (int)adj16[bb + lane] : 0;
    const int qsteps = (cnt + 3) >> 2;
    int it = 0;
    for (; it + 4 <= qsteps; it += 4) {
#pragma unroll
      for (int u = 0; u < 4; ++u) {
        const int e = 4 * (it + u) + g;
        const int s = __shfl(adjv, e);
        uint4 v = make_uint4(0u, 0u, 0u, 0u);
        if (act && e < cnt) v = *(const uint4*)(xb + (size_t)s * IN_DIM + foff);
        a0 += bflo(v.x); a1 += bfhi(v.x);
        a2 += bflo(v.y); a3 += bfhi(v.y);
        a4 += bflo(v.z); a5 += bfhi(v.z);
        a6 += bflo(v.w); a7 += bfhi(v.w);
      }
    }
    for (; it < qsteps; ++it) {
      const int e = 4 * it + g;
      const int s = __shfl(adjv, e);
      uint4 v = make_uint4(0u, 0u, 0u, 0u);
      if (act && e < cnt) v = *(const uint4*)(xb + (size_t)s * IN_DIM + foff);
      a0 += bflo(v.x); a1 += bfhi(v.x);
      a2 += bflo(v.y); a3 += bfhi(v.y);
      a4 += bflo(v.z); a5 += bfhi(v.z);
      a6 += bflo(v.w); a7 += bfhi(v.w);
    }
  }
  a0 += __shfl_xor(a0, 16); a0 += __shfl_xor(a0, 32);
  a1 += __shfl_xor(a1, 16); a1 += __shfl_xor(a1, 32);
  a2 += __shfl_xor(a2, 16); a2 += __shfl_xor(a2, 32);
  a3 += __shfl_xor(a3, 16); a3 += __shfl_xor(a3, 32);
  a4 += __shfl_xor(a4, 16); a4 += __shfl_xor(a4, 32);
  a5 += __shfl_xor(a5, 16); a5 += __shfl_xor(a5, 32);
  a6 += __shfl_xor(a6, 16); a6 += __shfl_xor(a6, 32);
  a7 += __shfl_xor(a7, 16); a7 += __shfl_xor(a7, 32);
  if (g == 0 && act) {
    const float inv = inv_deg[n];
    uint4 o;
    o.x = (uint32_t)f2bf(a0 * inv) | ((uint32_t)f2bf(a1 * inv) << 16);
    o.y = (uint32_t)f2bf(a2 * inv) | ((uint32_t)f2bf(a3 * inv) << 16);
    o.z = (uint32_t)f2bf(a4 * inv) | ((uint32_t)f2bf(a5 * inv) << 16);
    o.w = (uint32_t)f2bf(a6 * inv) | ((uint32_t)f2bf(a7 * inv) << 16);
    *(uint4*)(AGGb + (size_t)n * IN_DIM + foff) = o;
  }
}

// final: 4 subgroups x (16 lanes, uint2=8B) -> 128B T2b row.
__global__ __launch_bounds__(256) void final_kernel(const uint16_t* __restrict__ T2b,
    const float* __restrict__ R2, const uint16_t* __restrict__ adj16,
    const int* __restrict__ rowptr, const float* __restrict__ inv_deg,
    float* __restrict__ out, int nNodes) {
  const int wave = threadIdx.x >> 6;
  const int lane = threadIdx.x & 63;
  const int n = blockIdx.x * 4 + wave;
  if (n >= nNodes) return;
  const int beg = rowptr[n], end = rowptr[n + 1];
  const int g = lane >> 4;
  const int j = lane & 15;
  const int foff = j * 4;  // features 4j..4j+3
  float a0 = 0.f, a1 = 0.f, a2 = 0.f, a3 = 0.f;

  for (int bb = beg; bb < end; bb += 64) {
    const int cnt = min(64, end - bb);
    const int adjv = (lane < cnt) ? (int)adj16[bb + lane] : 0;
    const int qsteps = (cnt + 3) >> 2;
    int it = 0;
    for (; it + 4 <= qsteps; it += 4) {
#pragma unroll
      for (int u = 0; u < 4; ++u) {
        const int e = 4 * (it + u) + g;
        const int s = __shfl(adjv, e);
        uint2 v = make_uint2(0u, 0u);
        if (e < cnt) v = *(const uint2*)(T2b + (size_t)s * 64 + foff);
        a0 += bflo(v.x); a1 += bfhi(v.x);
        a2 += bflo(v.y); a3 += bfhi(v.y);
      }
    }
    for (; it < qsteps; ++it) {
      const int e = 4 * it + g;
      const int s = __shfl(adjv, e);
      uint2 v = make_uint2(0u, 0u);
      if (e < cnt) v = *(const uint2*)(T2b + (size_t)s * 64 + foff);
      a0 += bflo(v.x); a1 += bfhi(v.x);
      a2 += bflo(v.y); a3 += bfhi(v.y);
    }
  }
  a0 += __shfl_xor(a0, 16); a0 += __shfl_xor(a0, 32);
  a1 += __shfl_xor(a1, 16); a1 += __shfl_xor(a1, 32);
  a2 += __shfl_xor(a2, 16); a2 += __shfl_xor(a2, 32);
  a3 += __shfl_xor(a3, 16); a3 += __shfl_xor(a3, 32);
  if (g == 0) {
    const float inv = inv_deg[n];
    const float4 r = *(const float4*)(R2 + (size_t)n * 64 + foff);
    float4 o;
    o.x = a0 * inv + r.x;
    o.y = a1 * inv + r.y;
    o.z = a2 * inv + r.z;
    o.w = a3 * inv + r.w;
    *(float4*)(out + (size_t)n * 64 + foff) = o;
  }
}

// ---------------- fused MFMA GEMM1+GEMM2 ----------------
#define HPITCH 136
__global__ __launch_bounds__(256) void gemm12_kernel(
    const uint16_t* __restrict__ AGGb, const uint16_t* __restrict__ xb,
    const uint16_t* __restrict__ S1t, const uint16_t* __restrict__ S2t,
    const float* __restrict__ b1, const float* __restrict__ b2,
    uint16_t* __restrict__ T2b, float* __restrict__ R2, int M) {
  __shared__ uint16_t Hs[64][HPITCH];
  const int tid = threadIdx.x;
  const int wv = tid >> 6;
  const int lane = tid & 63;
  const int m16 = lane & 15;
  const int quad = lane >> 4;
  const int rowBase = blockIdx.x * 64 + wv * 16;
  int arow = rowBase + m16;
  if (arow >= M) arow = M - 1;  // clamp; stores guarded
  const int kq = quad * 8;

  // ---- GEMM1: [AGGb | xb] (K=192) @ S1t^T ----
  f32x4 acc[8];
#pragma unroll
  for (int cf = 0; cf < 8; ++cf) acc[cf] = (f32x4){0.f, 0.f, 0.f, 0.f};
  for (int k0 = 0; k0 < 192; k0 += 32) {
    const uint16_t* ap = (k0 < 96) ? (AGGb + (size_t)arow * IN_DIM + k0 + kq)
                                   : (xb + (size_t)arow * IN_DIM + (k0 - 96) + kq);
    const bf16x8 a = *(const bf16x8*)ap;
    bf16x8 b[8];
#pragma unroll
    for (int cf = 0; cf < 8; ++cf)
      b[cf] = *(const bf16x8*)(S1t + (size_t)(cf * 16 + m16) * 192 + k0 + kq);
#pragma unroll
    for (int cf = 0; cf < 8; ++cf)
      acc[cf] = __builtin_amdgcn_mfma_f32_16x16x32_bf16(a, b[cf], acc[cf], 0, 0, 0);
  }
  // epilogue1: relu(acc + b1) -> bf16 -> LDS H tile
#pragma unroll
  for (int cf = 0; cf < 8; ++cf) {
    const int col = cf * 16 + m16;
    const float bias = b1[col];
#pragma unroll
    for (int r = 0; r < 4; ++r) {
      const float v = fmaxf(acc[cf][r] + bias, 0.f);
      Hs[wv * 16 + quad * 4 + r][col] = f2bf(v);
    }
  }
  __syncthreads();

  // ---- GEMM2: H (K=128) @ S2t^T ----
  f32x4 acc2[8];
#pragma unroll
  for (int cf = 0; cf < 8; ++cf) acc2[cf] = (f32x4){0.f, 0.f, 0.f, 0.f};
  for (int k0 = 0; k0 < 128; k0 += 32) {
    const bf16x8 a = *(const bf16x8*)&Hs[wv * 16 + m16][k0 + kq];
    bf16x8 b[8];
#pragma unroll
    for (int cf = 0; cf < 8; ++cf)
      b[cf] = *(const bf16x8*)(S2t + (size_t)(cf * 16 + m16) * 128 + k0 + kq);
#pragma unroll
    for (int cf = 0; cf < 8; ++cf)
      acc2[cf] = __builtin_amdgcn_mfma_f32_16x16x32_bf16(a, b[cf], acc2[cf], 0, 0, 0);
  }
  // epilogue2: col<64 -> T2b bf16; col>=64 -> R2 f32 (+b2)
#pragma unroll
  for (int cf = 0; cf < 8; ++cf) {
    const int col = cf * 16 + m16;
#pragma unroll
    for (int r = 0; r < 4; ++r) {
      const int row = rowBase + quad * 4 + r;
      if (row < M) {
        const float v = acc2[cf][r];
        if (col < 64) {
          T2b[(size_t)row * 64 + col] = f2bf(v);
        } else {
          R2[(size_t)row * 64 + (col - 64)] = v + b2[col - 64];
        }
      }
    }
  }
}

extern "C" void kernel_launch(void* const* d_in, const int* in_sizes, int n_in,
                              void* d_out, int out_size, void* d_ws, size_t ws_size,
                              hipStream_t stream) {
  const float* x   = (const float*)d_in[0];
  const int*   ei  = (const int*)d_in[1];
  const float* w1l = (const float*)d_in[2];
  const float* b1  = (const float*)d_in[3];
  const float* w1r = (const float*)d_in[4];
  const float* w2l = (const float*)d_in[5];
  const float* b2  = (const float*)d_in[6];
  const float* w2r = (const float*)d_in[7];
  float* out = (float*)d_out;

  const int N = in_sizes[0] / IN_DIM;   // 50000
  const int E = in_sizes[1] / 2;        // 800000
  const int* src = ei;
  const int* dst = ei + E;
  const int NB = (N + 255) >> 8;        // 196 buckets

  // ---- workspace carve (AGGb DISJOINT from T2b/R2 — see round-7 bug note) ----
  char* p = (char*)d_ws;
  uint16_t* AGGb = (uint16_t*)p; p += alignUp((size_t)N * IN_DIM * sizeof(uint16_t), 256);
  uint16_t* T2b  = (uint16_t*)p; p += alignUp((size_t)N * 64 * sizeof(uint16_t), 256);
  float* R2      = (float*)p;    p += alignUp((size_t)N * 64 * sizeof(float), 256);
  uint16_t* xb = (uint16_t*)p; p += alignUp((size_t)N * IN_DIM * sizeof(uint16_t), 256);
  uint16_t* S1t = (uint16_t*)p; p += alignUp(NS1 * sizeof(uint16_t), 256);
  uint16_t* S2t = (uint16_t*)p; p += alignUp(NS2 * sizeof(uint16_t), 256);
  int* rowptr = (int*)p; p += alignUp((size_t)(N + 1) * sizeof(int), 256);
  float* inv_deg = (float*)p; p += alignUp((size_t)N * sizeof(float), 256);
  uint16_t* adj16 = (uint16_t*)p; p += alignUp((size_t)E * sizeof(uint16_t), 256);
  uint32_t* bucketBuf = (uint32_t*)p; p += alignUp((size_t)E * sizeof(uint32_t), 256);
  int* bucketCnt = (int*)p;    p += alignUp(256 * sizeof(int), 256);
  int* bucketBase = (int*)p;   p += alignUp(257 * sizeof(int), 256);
  int* bucketCursor = (int*)p; p += alignUp(256 * sizeof(int), 256);
  (void)ws_size; (void)n_in; (void)out_size;

  hipMemsetAsync(bucketCnt, 0, 256 * sizeof(int), stream);

  bucket_count_kernel<<<256, 256, 0, stream>>>(dst, bucketCnt, E);
  bucket_scan_kernel<<<1, 256, 0, stream>>>(bucketCnt, bucketBase, bucketCursor, rowptr, NB, N);
  bucket_scatter_kernel<<<(E + SCAT_CHUNK - 1) / SCAT_CHUNK, 256, 0, stream>>>(
      src, dst, bucketCursor, bucketBuf, E);
  bucket_build_kernel<<<NB, 256, 0, stream>>>(bucketBuf, bucketBase, rowptr, inv_deg, adj16, N);

  const int total4 = N * IN_DIM / 4;
  const int prepThreads = NS1 + NS2 + total4;
  prep_kernel<<<(prepThreads + 255) / 256, 256, 0, stream>>>(x, w1l, w1r, w2l, w2r,
                                                             S1t, S2t, xb, total4);

  const int nodeBlocks = (N + 3) / 4;
  agg1_kernel<<<nodeBlocks, 256, 0, stream>>>(xb, adj16, rowptr, inv_deg, AGGb, N);

  const int gemmBlocks = (N + 63) / 64;
  gemm12_kernel<<<gemmBlocks, 256, 0, stream>>>(AGGb, xb, S1t, S2t, b1, b2, T2b, R2, N);

  final_kernel<<<nodeBlocks, 256, 0, stream>>>(T2b, R2, adj16, rowptr, inv_deg, out, N);
}

// Round 9
// 216.912 us; speedup vs baseline: 2.4807x; 1.0054x over previous
//
#include <hip/hip_runtime.h>
#include <cstdint>
#include <cstddef>

// BinSAGE: 2-layer GraphSAGE with sign-binarized weights. MFMA bf16 + bucket-sort CSR.
// N=50000 nodes, E=800000 edges, dims 96 -> 128 -> 64.
//   CSR build: bucket counting sort (196 buckets of 256 nodes), adj stored u16.
//   prep (1 dispatch): S1t/S2t sign matrices bf16 + xb = bf16(x)
//   agg1: mean of xb over in-edges -> AGGb bf16 [N,96]
//   gemm12 (fused, MFMA): [AGGb|xb] @ S1t^T -> relu -> H (per-wave LDS tile)
//                         H @ S2t^T -> T2b bf16 [N,64] + R2 f32 [N,64]
//   final: out = inv_deg * segsum(T2b[src]) + R2
// Round-8 lesson: the compiler sank the 8 B-frag loads one-by-one next to their
// MFMAs (VGPR=68, MfmaUtil=3%, ~37k cyc/block => 90 serial L2 round-trips).
// Fix: explicit double-buffered prefetch + __builtin_amdgcn_sched_barrier(0)
// after each load batch so all loads of a k-step issue before any MFMA.
// Also: H tile is wave-private -> NO __syncthreads (its vmcnt(0) drain would
// kill the cross-phase S2t prefetch). Gathers get the same batch-pinning.

#define N_NODES 50000
#define IN_DIM 96
#define HID 128
#define OUT_DIM 64

typedef __attribute__((ext_vector_type(8))) short bf16x8;
typedef __attribute__((ext_vector_type(4))) float f32x4;

static inline size_t alignUp(size_t v, size_t a) { return (v + a - 1) & ~(a - 1); }

__device__ __forceinline__ uint16_t f2bf(float f) {
  uint32_t u = __float_as_uint(f);
  return (uint16_t)((u + 0x7FFF + ((u >> 16) & 1)) >> 16);
}
__device__ __forceinline__ float bflo(uint32_t v) { return __uint_as_float(v << 16); }
__device__ __forceinline__ float bfhi(uint32_t v) { return __uint_as_float(v & 0xFFFF0000u); }

// ---------------- CSR build: bucketed counting sort ----------------
__global__ __launch_bounds__(256) void bucket_count_kernel(const int* __restrict__ dst,
    int* __restrict__ bucketCnt, int E) {
  __shared__ int h[256];
  const int t = threadIdx.x;
  h[t] = 0;
  __syncthreads();
  const int stride = gridDim.x * 256;
  for (int i = blockIdx.x * 256 + t; i < E; i += stride)
    atomicAdd(&h[dst[i] >> 8], 1);
  __syncthreads();
  if (h[t]) atomicAdd(&bucketCnt[t], h[t]);
}

__global__ __launch_bounds__(256) void bucket_scan_kernel(const int* __restrict__ bucketCnt,
    int* __restrict__ bucketBase, int* __restrict__ bucketCursor, int* __restrict__ rowptr,
    int nB, int N) {
  __shared__ int smem[256];
  const int t = threadIdx.x;
  const int v = (t < nB) ? bucketCnt[t] : 0;
  smem[t] = v;
  __syncthreads();
  for (int off = 1; off < 256; off <<= 1) {
    int u = (t >= off) ? smem[t - off] : 0;
    __syncthreads();
    smem[t] += u;
    __syncthreads();
  }
  if (t < nB) {
    const int excl = smem[t] - v;
    bucketBase[t] = excl;
    bucketCursor[t] = excl;
  }
  if (t == 255) {
    bucketBase[nB] = smem[255];
    rowptr[N] = smem[255];
  }
}

#define SCAT_CHUNK 2048
__global__ __launch_bounds__(256) void bucket_scatter_kernel(const int* __restrict__ src,
    const int* __restrict__ dst, int* __restrict__ bucketCursor,
    uint32_t* __restrict__ bucketBuf, int E) {
  __shared__ int h[256];
  __shared__ int g[256];
  __shared__ int c[256];
  const int t = threadIdx.x;
  const int base = blockIdx.x * SCAT_CHUNK;
  const int end = min(base + SCAT_CHUNK, E);
  h[t] = 0;
  __syncthreads();
  for (int i = base + t; i < end; i += 256)
    atomicAdd(&h[dst[i] >> 8], 1);
  __syncthreads();
  if (h[t]) g[t] = atomicAdd(&bucketCursor[t], h[t]);
  c[t] = 0;
  __syncthreads();
  for (int i = base + t; i < end; i += 256) {
    const int d = dst[i];
    const int b = d >> 8;
    const int ticket = atomicAdd(&c[b], 1);
    bucketBuf[g[b] + ticket] = (uint32_t)src[i] | ((uint32_t)(d & 255) << 16);
  }
}

__global__ __launch_bounds__(256) void bucket_build_kernel(const uint32_t* __restrict__ bucketBuf,
    const int* __restrict__ bucketBase, int* __restrict__ rowptr, float* __restrict__ inv_deg,
    uint16_t* __restrict__ adj16, int N) {
  __shared__ int h[256];
  __shared__ int s[256];
  __shared__ int cur[256];
  const int t = threadIdx.x;
  const int b = blockIdx.x;
  const int nodeBase = b << 8;
  const int beg = bucketBase[b], end = bucketBase[b + 1];
  const int m = end - beg;
  h[t] = 0;
  __syncthreads();
  for (int i = t; i < m; i += 256)
    atomicAdd(&h[(bucketBuf[beg + i] >> 16) & 255], 1);
  __syncthreads();
  const int d = h[t];
  s[t] = d;
  __syncthreads();
  for (int off = 1; off < 256; off <<= 1) {
    int u = (t >= off) ? s[t - off] : 0;
    __syncthreads();
    s[t] += u;
    __syncthreads();
  }
  const int excl = s[t] - d;
  const int node = nodeBase + t;
  if (node < N) {
    rowptr[node] = beg + excl;
    inv_deg[node] = 1.0f / (float)(d > 1 ? d : 1);
  }
  cur[t] = excl;
  __syncthreads();
  for (int i = t; i < m; i += 256) {
    const uint32_t u = bucketBuf[beg + i];
    const int ld = (u >> 16) & 255;
    const int ticket = atomicAdd(&cur[ld], 1);
    adj16[beg + ticket] = (uint16_t)(u & 0xFFFFu);
  }
}

// ---------------- combined prep: sign matrices + x->bf16 ----------------
__device__ __forceinline__ uint16_t sgnbf(float w) {
  return (w > 0.f) ? (uint16_t)0x3F80 : ((w < 0.f) ? (uint16_t)0xBF80 : (uint16_t)0);
}

#define NS1 (128 * 192)
#define NS2 (128 * 128)
__global__ __launch_bounds__(256) void prep_kernel(const float* __restrict__ x,
    const float* __restrict__ w1l, const float* __restrict__ w1r,
    const float* __restrict__ w2l, const float* __restrict__ w2r,
    uint16_t* __restrict__ S1t, uint16_t* __restrict__ S2t,
    uint16_t* __restrict__ xb, int total4) {
  int idx = blockIdx.x * blockDim.x + threadIdx.x;
  if (idx < NS1) {
    int n = idx / 192, k = idx - n * 192;
    float w = (k < 96) ? w1l[n * 96 + k] : w1r[n * 96 + (k - 96)];
    S1t[idx] = sgnbf(w);
  } else if (idx < NS1 + NS2) {
    int i2 = idx - NS1;
    int n = i2 >> 7, k = i2 & 127;
    float w = (n < 64) ? w2l[n * 128 + k] : w2r[(n - 64) * 128 + k];
    S2t[i2] = sgnbf(w);
  } else {
    int i = idx - NS1 - NS2;
    if (i < total4) {
      float4 v = *(const float4*)(x + (size_t)i * 4);
      uint32_t p0 = (uint32_t)f2bf(v.x) | ((uint32_t)f2bf(v.y) << 16);
      uint32_t p1 = (uint32_t)f2bf(v.z) | ((uint32_t)f2bf(v.w) << 16);
      *(uint2*)(xb + (size_t)i * 4) = make_uint2(p0, p1);
    }
  }
}

// ---------------- gathers ----------------
// Wave per node; 4 subgroups of 16 lanes each gather a different edge.
// Loads batched (v[4]) and pinned before the accumulate via sched_barrier(0).
__global__ __launch_bounds__(256) void agg1_kernel(const uint16_t* __restrict__ xb,
    const uint16_t* __restrict__ adj16, const int* __restrict__ rowptr,
    const float* __restrict__ inv_deg, uint16_t* __restrict__ AGGb, int nNodes) {
  const int wave = threadIdx.x >> 6;
  const int lane = threadIdx.x & 63;
  const int n = blockIdx.x * 4 + wave;
  if (n >= nNodes) return;
  const int beg = rowptr[n], end = rowptr[n + 1];
  const int g = lane >> 4;
  const int j = lane & 15;
  const bool act = j < 12;
  const int foff = j * 8;  // features 8j..8j+7
  float a0 = 0.f, a1 = 0.f, a2 = 0.f, a3 = 0.f, a4 = 0.f, a5 = 0.f, a6 = 0.f, a7 = 0.f;

  for (int bb = beg; bb < end; bb += 64) {
    const int cnt = min(64, end - bb);
    const int adjv = (lane < cnt) ? (int)adj16[bb + lane] : 0;
    const int qsteps = (cnt + 3) >> 2;
    int it = 0;
    for (; it + 4 <= qsteps; it += 4) {
      uint4 v[4];
#pragma unroll
      for (int u = 0; u < 4; ++u) {
        const int e = 4 * (it + u) + g;
        const int s = __shfl(adjv, e);
        v[u] = make_uint4(0u, 0u, 0u, 0u);
        if (act && e < cnt) v[u] = *(const uint4*)(xb + (size_t)s * IN_DIM + foff);
      }
      __builtin_amdgcn_sched_barrier(0);
#pragma unroll
      for (int u = 0; u < 4; ++u) {
        a0 += bflo(v[u].x); a1 += bfhi(v[u].x);
        a2 += bflo(v[u].y); a3 += bfhi(v[u].y);
        a4 += bflo(v[u].z); a5 += bfhi(v[u].z);
        a6 += bflo(v[u].w); a7 += bfhi(v[u].w);
      }
    }
    for (; it < qsteps; ++it) {
      const int e = 4 * it + g;
      const int s = __shfl(adjv, e);
      uint4 v = make_uint4(0u, 0u, 0u, 0u);
      if (act && e < cnt) v = *(const uint4*)(xb + (size_t)s * IN_DIM + foff);
      a0 += bflo(v.x); a1 += bfhi(v.x);
      a2 += bflo(v.y); a3 += bfhi(v.y);
      a4 += bflo(v.z); a5 += bfhi(v.z);
      a6 += bflo(v.w); a7 += bfhi(v.w);
    }
  }
  a0 += __shfl_xor(a0, 16); a0 += __shfl_xor(a0, 32);
  a1 += __shfl_xor(a1, 16); a1 += __shfl_xor(a1, 32);
  a2 += __shfl_xor(a2, 16); a2 += __shfl_xor(a2, 32);
  a3 += __shfl_xor(a3, 16); a3 += __shfl_xor(a3, 32);
  a4 += __shfl_xor(a4, 16); a4 += __shfl_xor(a4, 32);
  a5 += __shfl_xor(a5, 16); a5 += __shfl_xor(a5, 32);
  a6 += __shfl_xor(a6, 16); a6 += __shfl_xor(a6, 32);
  a7 += __shfl_xor(a7, 16); a7 += __shfl_xor(a7, 32);
  if (g == 0 && act) {
    const float inv = inv_deg[n];
    uint4 o;
    o.x = (uint32_t)f2bf(a0 * inv) | ((uint32_t)f2bf(a1 * inv) << 16);
    o.y = (uint32_t)f2bf(a2 * inv) | ((uint32_t)f2bf(a3 * inv) << 16);
    o.z = (uint32_t)f2bf(a4 * inv) | ((uint32_t)f2bf(a5 * inv) << 16);
    o.w = (uint32_t)f2bf(a6 * inv) | ((uint32_t)f2bf(a7 * inv) << 16);
    *(uint4*)(AGGb + (size_t)n * IN_DIM + foff) = o;
  }
}

// final: 4 subgroups x (16 lanes, uint2=8B) -> 128B T2b row. Batched loads.
__global__ __launch_bounds__(256) void final_kernel(const uint16_t* __restrict__ T2b,
    const float* __restrict__ R2, const uint16_t* __restrict__ adj16,
    const int* __restrict__ rowptr, const float* __restrict__ inv_deg,
    float* __restrict__ out, int nNodes) {
  const int wave = threadIdx.x >> 6;
  const int lane = threadIdx.x & 63;
  const int n = blockIdx.x * 4 + wave;
  if (n >= nNodes) return;
  const int beg = rowptr[n], end = rowptr[n + 1];
  const int g = lane >> 4;
  const int j = lane & 15;
  const int foff = j * 4;  // features 4j..4j+3
  float a0 = 0.f, a1 = 0.f, a2 = 0.f, a3 = 0.f;

  for (int bb = beg; bb < end; bb += 64) {
    const int cnt = min(64, end - bb);
    const int adjv = (lane < cnt) ? (int)adj16[bb + lane] : 0;
    const int qsteps = (cnt + 3) >> 2;
    int it = 0;
    for (; it + 4 <= qsteps; it += 4) {
      uint2 v[4];
#pragma unroll
      for (int u = 0; u < 4; ++u) {
        const int e = 4 * (it + u) + g;
        const int s = __shfl(adjv, e);
        v[u] = make_uint2(0u, 0u);
        if (e < cnt) v[u] = *(const uint2*)(T2b + (size_t)s * 64 + foff);
      }
      __builtin_amdgcn_sched_barrier(0);
#pragma unroll
      for (int u = 0; u < 4; ++u) {
        a0 += bflo(v[u].x); a1 += bfhi(v[u].x);
        a2 += bflo(v[u].y); a3 += bfhi(v[u].y);
      }
    }
    for (; it < qsteps; ++it) {
      const int e = 4 * it + g;
      const int s = __shfl(adjv, e);
      uint2 v = make_uint2(0u, 0u);
      if (e < cnt) v = *(const uint2*)(T2b + (size_t)s * 64 + foff);
      a0 += bflo(v.x); a1 += bfhi(v.x);
      a2 += bflo(v.y); a3 += bfhi(v.y);
    }
  }
  a0 += __shfl_xor(a0, 16); a0 += __shfl_xor(a0, 32);
  a1 += __shfl_xor(a1, 16); a1 += __shfl_xor(a1, 32);
  a2 += __shfl_xor(a2, 16); a2 += __shfl_xor(a2, 32);
  a3 += __shfl_xor(a3, 16); a3 += __shfl_xor(a3, 32);
  if (g == 0) {
    const float inv = inv_deg[n];
    const float4 r = *(const float4*)(R2 + (size_t)n * 64 + foff);
    float4 o;
    o.x = a0 * inv + r.x;
    o.y = a1 * inv + r.y;
    o.z = a2 * inv + r.z;
    o.w = a3 * inv + r.w;
    *(float4*)(out + (size_t)n * 64 + foff) = o;
  }
}

// ---------------- fused MFMA GEMM1+GEMM2, software-pipelined ----------------
// Block = 4 waves = 64 rows; wave = 16 rows x 128 cols. H tile is WAVE-PRIVATE
// (each wave writes/reads only rows [wv*16, wv*16+16)) -> no __syncthreads.
#define HPITCH 136
__global__ __launch_bounds__(256) void gemm12_kernel(
    const uint16_t* __restrict__ AGGb, const uint16_t* __restrict__ xb,
    const uint16_t* __restrict__ S1t, const uint16_t* __restrict__ S2t,
    const float* __restrict__ b1, const float* __restrict__ b2,
    uint16_t* __restrict__ T2b, float* __restrict__ R2, int M) {
  __shared__ uint16_t Hs[64][HPITCH];
  const int tid = threadIdx.x;
  const int wv = tid >> 6;
  const int lane = tid & 63;
  const int m16 = lane & 15;
  const int quad = lane >> 4;
  const int rowBase = blockIdx.x * 64 + wv * 16;
  int arow = rowBase + m16;
  if (arow >= M) arow = M - 1;  // clamp; stores guarded
  const int kq = quad * 8;

  const uint16_t* aRow0 = AGGb + (size_t)arow * IN_DIM + kq;  // k0 in {0,32,64}
  const uint16_t* aRow1 = xb + (size_t)arow * IN_DIM + kq;    // k0 in {96,128,160}

  bf16x8 aCur, aNxt, bCur[8], bNxt[8];

  // ---- GEMM1: [AGGb | xb] (K=192) @ S1t^T, rolling prefetch ----
  f32x4 acc1[8];
#pragma unroll
  for (int cf = 0; cf < 8; ++cf) acc1[cf] = (f32x4){0.f, 0.f, 0.f, 0.f};

  aCur = *(const bf16x8*)(aRow0);
#pragma unroll
  for (int cf = 0; cf < 8; ++cf)
    bCur[cf] = *(const bf16x8*)(S1t + (size_t)(cf * 16 + m16) * 192 + kq);

#pragma unroll
  for (int s = 0; s < 6; ++s) {
    if (s < 5) {
      const int k0n = (s + 1) * 32;
      aNxt = (k0n < 96) ? *(const bf16x8*)(aRow0 + k0n)
                        : *(const bf16x8*)(aRow1 + (k0n - 96));
#pragma unroll
      for (int cf = 0; cf < 8; ++cf)
        bNxt[cf] = *(const bf16x8*)(S1t + (size_t)(cf * 16 + m16) * 192 + k0n + kq);
    } else {
      // cross-phase prefetch: gemm2 step-0 B from S2t
#pragma unroll
      for (int cf = 0; cf < 8; ++cf)
        bNxt[cf] = *(const bf16x8*)(S2t + (size_t)(cf * 16 + m16) * 128 + kq);
    }
    __builtin_amdgcn_sched_barrier(0);  // all loads issue before MFMAs
#pragma unroll
    for (int cf = 0; cf < 8; ++cf)
      acc1[cf] = __builtin_amdgcn_mfma_f32_16x16x32_bf16(aCur, bCur[cf], acc1[cf], 0, 0, 0);
    if (s < 5) aCur = aNxt;
#pragma unroll
    for (int cf = 0; cf < 8; ++cf) bCur[cf] = bNxt[cf];
  }

  // epilogue1: relu(acc1 + b1) -> bf16 -> wave-private LDS H tile
#pragma unroll
  for (int cf = 0; cf < 8; ++cf) {
    const int col = cf * 16 + m16;
    const float bias = b1[col];
#pragma unroll
    for (int r = 0; r < 4; ++r) {
      const float v = fmaxf(acc1[cf][r] + bias, 0.f);
      Hs[wv * 16 + quad * 4 + r][col] = f2bf(v);
    }
  }
  // no __syncthreads: each wave reads only its own rows (lgkmcnt orders ds ops)

  // ---- GEMM2: H (K=128) @ S2t^T, rolling prefetch (bCur preloaded above) ----
  f32x4 acc2[8];
#pragma unroll
  for (int cf = 0; cf < 8; ++cf) acc2[cf] = (f32x4){0.f, 0.f, 0.f, 0.f};

  aCur = *(const bf16x8*)&Hs[wv * 16 + m16][kq];
#pragma unroll
  for (int s = 0; s < 4; ++s) {
    if (s < 3) {
      const int k0n = (s + 1) * 32;
#pragma unroll
      for (int cf = 0; cf < 8; ++cf)
        bNxt[cf] = *(const bf16x8*)(S2t + (size_t)(cf * 16 + m16) * 128 + k0n + kq);
      aNxt = *(const bf16x8*)&Hs[wv * 16 + m16][k0n + kq];
    }
    __builtin_amdgcn_sched_barrier(0);
#pragma unroll
    for (int cf = 0; cf < 8; ++cf)
      acc2[cf] = __builtin_amdgcn_mfma_f32_16x16x32_bf16(aCur, bCur[cf], acc2[cf], 0, 0, 0);
    if (s < 3) {
      aCur = aNxt;
#pragma unroll
      for (int cf = 0; cf < 8; ++cf) bCur[cf] = bNxt[cf];
    }
  }

  // epilogue2: col<64 -> T2b bf16; col>=64 -> R2 f32 (+b2)
#pragma unroll
  for (int cf = 0; cf < 8; ++cf) {
    const int col = cf * 16 + m16;
#pragma unroll
    for (int r = 0; r < 4; ++r) {
      const int row = rowBase + quad * 4 + r;
      if (row < M) {
        const float v = acc2[cf][r];
        if (col < 64) {
          T2b[(size_t)row * 64 + col] = f2bf(v);
        } else {
          R2[(size_t)row * 64 + (col - 64)] = v + b2[col - 64];
        }
      }
    }
  }
}

extern "C" void kernel_launch(void* const* d_in, const int* in_sizes, int n_in,
                              void* d_out, int out_size, void* d_ws, size_t ws_size,
                              hipStream_t stream) {
  const float* x   = (const float*)d_in[0];
  const int*   ei  = (const int*)d_in[1];
  const float* w1l = (const float*)d_in[2];
  const float* b1  = (const float*)d_in[3];
  const float* w1r = (const float*)d_in[4];
  const float* w2l = (const float*)d_in[5];
  const float* b2  = (const float*)d_in[6];
  const float* w2r = (const float*)d_in[7];
  float* out = (float*)d_out;

  const int N = in_sizes[0] / IN_DIM;   // 50000
  const int E = in_sizes[1] / 2;        // 800000
  const int* src = ei;
  const int* dst = ei + E;
  const int NB = (N + 255) >> 8;        // 196 buckets

  // ---- workspace carve (AGGb DISJOINT from T2b/R2 — round-7 bug) ----
  char* p = (char*)d_ws;
  uint16_t* AGGb = (uint16_t*)p; p += alignUp((size_t)N * IN_DIM * sizeof(uint16_t), 256);
  uint16_t* T2b  = (uint16_t*)p; p += alignUp((size_t)N * 64 * sizeof(uint16_t), 256);
  float* R2      = (float*)p;    p += alignUp((size_t)N * 64 * sizeof(float), 256);
  uint16_t* xb = (uint16_t*)p; p += alignUp((size_t)N * IN_DIM * sizeof(uint16_t), 256);
  uint16_t* S1t = (uint16_t*)p; p += alignUp(NS1 * sizeof(uint16_t), 256);
  uint16_t* S2t = (uint16_t*)p; p += alignUp(NS2 * sizeof(uint16_t), 256);
  int* rowptr = (int*)p; p += alignUp((size_t)(N + 1) * sizeof(int), 256);
  float* inv_deg = (float*)p; p += alignUp((size_t)N * sizeof(float), 256);
  uint16_t* adj16 = (uint16_t*)p; p += alignUp((size_t)E * sizeof(uint16_t), 256);
  uint32_t* bucketBuf = (uint32_t*)p; p += alignUp((size_t)E * sizeof(uint32_t), 256);
  int* bucketCnt = (int*)p;    p += alignUp(256 * sizeof(int), 256);
  int* bucketBase = (int*)p;   p += alignUp(257 * sizeof(int), 256);
  int* bucketCursor = (int*)p; p += alignUp(256 * sizeof(int), 256);
  (void)ws_size; (void)n_in; (void)out_size;

  hipMemsetAsync(bucketCnt, 0, 256 * sizeof(int), stream);

  bucket_count_kernel<<<256, 256, 0, stream>>>(dst, bucketCnt, E);
  bucket_scan_kernel<<<1, 256, 0, stream>>>(bucketCnt, bucketBase, bucketCursor, rowptr, NB, N);
  bucket_scatter_kernel<<<(E + SCAT_CHUNK - 1) / SCAT_CHUNK, 256, 0, stream>>>(
      src, dst, bucketCursor, bucketBuf, E);
  bucket_build_kernel<<<NB, 256, 0, stream>>>(bucketBuf, bucketBase, rowptr, inv_deg, adj16, N);

  const int total4 = N * IN_DIM / 4;
  const int prepThreads = NS1 + NS2 + total4;
  prep_kernel<<<(prepThreads + 255) / 256, 256, 0, stream>>>(x, w1l, w1r, w2l, w2r,
                                                             S1t, S2t, xb, total4);

  const int nodeBlocks = (N + 3) / 4;
  agg1_kernel<<<nodeBlocks, 256, 0, stream>>>(xb, adj16, rowptr, inv_deg, AGGb, N);

  const int gemmBlocks = (N + 63) / 64;
  gemm12_kernel<<<gemmBlocks, 256, 0, stream>>>(AGGb, xb, S1t, S2t, b1, b2, T2b, R2, N);

  final_kernel<<<nodeBlocks, 256, 0, stream>>>(T2b, R2, adj16, rowptr, inv_deg, out, N);
}

// Round 10
// 188.155 us; speedup vs baseline: 2.8598x; 1.1528x over previous
//
#include <hip/hip_runtime.h>
#include <cstdint>
#include <cstddef>

// BinSAGE: 2-layer GraphSAGE with sign-binarized weights. MFMA bf16 + bucket-sort CSR.
// N=50000 nodes, E=800000 edges, dims 96 -> 128 -> 64.
//   CSR build: bucket counting sort (196 buckets of 256 nodes), adj stored u16.
//   prep (1 dispatch): S1t/S2t sign matrices bf16 + xb = bf16(x)
//   agg1: mean of xb over in-edges -> AGGb bf16 [N,96]
//   gemm12 (fused, MFMA, B staged in LDS): [AGGb|xb] @ S1t^T -> relu -> H (LDS)
//                                          H @ S2t^T -> T2b bf16 + R2 f32
//   final: out = inv_deg * segsum(T2b[src]) + R2
// Round-9 lesson: no-LDS GEMM makes EVERY wave read the whole B matrix
// (3128 waves x 81KB = 253MB through per-CU L1/L2) and the k-loop load chain
// serializes (46us, MfmaUtil 3%, ~1.2k cyc/load). Register prefetch + sched
// barriers did NOT fix it (R9: identical counters). Fix: stage B in LDS once
// per block (pitch 200/136 -> bank-uniform b128 reads), preload all A-frags,
// k-loop = ds_read + MFMA only. B global traffic 253MB -> 63MB.

#define N_NODES 50000
#define IN_DIM 96
#define HID 128
#define OUT_DIM 64

typedef __attribute__((ext_vector_type(8))) short bf16x8;
typedef __attribute__((ext_vector_type(4))) float f32x4;

static inline size_t alignUp(size_t v, size_t a) { return (v + a - 1) & ~(a - 1); }

__device__ __forceinline__ uint16_t f2bf(float f) {
  uint32_t u = __float_as_uint(f);
  return (uint16_t)((u + 0x7FFF + ((u >> 16) & 1)) >> 16);
}
__device__ __forceinline__ float bflo(uint32_t v) { return __uint_as_float(v << 16); }
__device__ __forceinline__ float bfhi(uint32_t v) { return __uint_as_float(v & 0xFFFF0000u); }

// ---------------- CSR build: bucketed counting sort ----------------
__global__ __launch_bounds__(256) void bucket_count_kernel(const int* __restrict__ dst,
    int* __restrict__ bucketCnt, int E) {
  __shared__ int h[256];
  const int t = threadIdx.x;
  h[t] = 0;
  __syncthreads();
  const int stride = gridDim.x * 256;
  for (int i = blockIdx.x * 256 + t; i < E; i += stride)
    atomicAdd(&h[dst[i] >> 8], 1);
  __syncthreads();
  if (h[t]) atomicAdd(&bucketCnt[t], h[t]);
}

__global__ __launch_bounds__(256) void bucket_scan_kernel(const int* __restrict__ bucketCnt,
    int* __restrict__ bucketBase, int* __restrict__ bucketCursor, int* __restrict__ rowptr,
    int nB, int N) {
  __shared__ int smem[256];
  const int t = threadIdx.x;
  const int v = (t < nB) ? bucketCnt[t] : 0;
  smem[t] = v;
  __syncthreads();
  for (int off = 1; off < 256; off <<= 1) {
    int u = (t >= off) ? smem[t - off] : 0;
    __syncthreads();
    smem[t] += u;
    __syncthreads();
  }
  if (t < nB) {
    const int excl = smem[t] - v;
    bucketBase[t] = excl;
    bucketCursor[t] = excl;
  }
  if (t == 255) {
    bucketBase[nB] = smem[255];
    rowptr[N] = smem[255];
  }
}

#define SCAT_CHUNK 2048
__global__ __launch_bounds__(256) void bucket_scatter_kernel(const int* __restrict__ src,
    const int* __restrict__ dst, int* __restrict__ bucketCursor,
    uint32_t* __restrict__ bucketBuf, int E) {
  __shared__ int h[256];
  __shared__ int g[256];
  __shared__ int c[256];
  const int t = threadIdx.x;
  const int base = blockIdx.x * SCAT_CHUNK;
  const int end = min(base + SCAT_CHUNK, E);
  h[t] = 0;
  __syncthreads();
  for (int i = base + t; i < end; i += 256)
    atomicAdd(&h[dst[i] >> 8], 1);
  __syncthreads();
  if (h[t]) g[t] = atomicAdd(&bucketCursor[t], h[t]);
  c[t] = 0;
  __syncthreads();
  for (int i = base + t; i < end; i += 256) {
    const int d = dst[i];
    const int b = d >> 8;
    const int ticket = atomicAdd(&c[b], 1);
    bucketBuf[g[b] + ticket] = (uint32_t)src[i] | ((uint32_t)(d & 255) << 16);
  }
}

__global__ __launch_bounds__(256) void bucket_build_kernel(const uint32_t* __restrict__ bucketBuf,
    const int* __restrict__ bucketBase, int* __restrict__ rowptr, float* __restrict__ inv_deg,
    uint16_t* __restrict__ adj16, int N) {
  __shared__ int h[256];
  __shared__ int s[256];
  __shared__ int cur[256];
  const int t = threadIdx.x;
  const int b = blockIdx.x;
  const int nodeBase = b << 8;
  const int beg = bucketBase[b], end = bucketBase[b + 1];
  const int m = end - beg;
  h[t] = 0;
  __syncthreads();
  for (int i = t; i < m; i += 256)
    atomicAdd(&h[(bucketBuf[beg + i] >> 16) & 255], 1);
  __syncthreads();
  const int d = h[t];
  s[t] = d;
  __syncthreads();
  for (int off = 1; off < 256; off <<= 1) {
    int u = (t >= off) ? s[t - off] : 0;
    __syncthreads();
    s[t] += u;
    __syncthreads();
  }
  const int excl = s[t] - d;
  const int node = nodeBase + t;
  if (node < N) {
    rowptr[node] = beg + excl;
    inv_deg[node] = 1.0f / (float)(d > 1 ? d : 1);
  }
  cur[t] = excl;
  __syncthreads();
  for (int i = t; i < m; i += 256) {
    const uint32_t u = bucketBuf[beg + i];
    const int ld = (u >> 16) & 255;
    const int ticket = atomicAdd(&cur[ld], 1);
    adj16[beg + ticket] = (uint16_t)(u & 0xFFFFu);
  }
}

// ---------------- combined prep: sign matrices + x->bf16 ----------------
__device__ __forceinline__ uint16_t sgnbf(float w) {
  return (w > 0.f) ? (uint16_t)0x3F80 : ((w < 0.f) ? (uint16_t)0xBF80 : (uint16_t)0);
}

#define NS1 (128 * 192)
#define NS2 (128 * 128)
__global__ __launch_bounds__(256) void prep_kernel(const float* __restrict__ x,
    const float* __restrict__ w1l, const float* __restrict__ w1r,
    const float* __restrict__ w2l, const float* __restrict__ w2r,
    uint16_t* __restrict__ S1t, uint16_t* __restrict__ S2t,
    uint16_t* __restrict__ xb, int total4) {
  int idx = blockIdx.x * blockDim.x + threadIdx.x;
  if (idx < NS1) {
    int n = idx / 192, k = idx - n * 192;
    float w = (k < 96) ? w1l[n * 96 + k] : w1r[n * 96 + (k - 96)];
    S1t[idx] = sgnbf(w);
  } else if (idx < NS1 + NS2) {
    int i2 = idx - NS1;
    int n = i2 >> 7, k = i2 & 127;
    float w = (n < 64) ? w2l[n * 128 + k] : w2r[(n - 64) * 128 + k];
    S2t[i2] = sgnbf(w);
  } else {
    int i = idx - NS1 - NS2;
    if (i < total4) {
      float4 v = *(const float4*)(x + (size_t)i * 4);
      uint32_t p0 = (uint32_t)f2bf(v.x) | ((uint32_t)f2bf(v.y) << 16);
      uint32_t p1 = (uint32_t)f2bf(v.z) | ((uint32_t)f2bf(v.w) << 16);
      *(uint2*)(xb + (size_t)i * 4) = make_uint2(p0, p1);
    }
  }
}

// ---------------- gathers (unchanged from R9) ----------------
__global__ __launch_bounds__(256) void agg1_kernel(const uint16_t* __restrict__ xb,
    const uint16_t* __restrict__ adj16, const int* __restrict__ rowptr,
    const float* __restrict__ inv_deg, uint16_t* __restrict__ AGGb, int nNodes) {
  const int wave = threadIdx.x >> 6;
  const int lane = threadIdx.x & 63;
  const int n = blockIdx.x * 4 + wave;
  if (n >= nNodes) return;
  const int beg = rowptr[n], end = rowptr[n + 1];
  const int g = lane >> 4;
  const int j = lane & 15;
  const bool act = j < 12;
  const int foff = j * 8;
  float a0 = 0.f, a1 = 0.f, a2 = 0.f, a3 = 0.f, a4 = 0.f, a5 = 0.f, a6 = 0.f, a7 = 0.f;

  for (int bb = beg; bb < end; bb += 64) {
    const int cnt = min(64, end - bb);
    const int adjv = (lane < cnt) ? (int)adj16[bb + lane] : 0;
    const int qsteps = (cnt + 3) >> 2;
    int it = 0;
    for (; it + 4 <= qsteps; it += 4) {
      uint4 v[4];
#pragma unroll
      for (int u = 0; u < 4; ++u) {
        const int e = 4 * (it + u) + g;
        const int s = __shfl(adjv, e);
        v[u] = make_uint4(0u, 0u, 0u, 0u);
        if (act && e < cnt) v[u] = *(const uint4*)(xb + (size_t)s * IN_DIM + foff);
      }
      __builtin_amdgcn_sched_barrier(0);
#pragma unroll
      for (int u = 0; u < 4; ++u) {
        a0 += bflo(v[u].x); a1 += bfhi(v[u].x);
        a2 += bflo(v[u].y); a3 += bfhi(v[u].y);
        a4 += bflo(v[u].z); a5 += bfhi(v[u].z);
        a6 += bflo(v[u].w); a7 += bfhi(v[u].w);
      }
    }
    for (; it < qsteps; ++it) {
      const int e = 4 * it + g;
      const int s = __shfl(adjv, e);
      uint4 v = make_uint4(0u, 0u, 0u, 0u);
      if (act && e < cnt) v = *(const uint4*)(xb + (size_t)s * IN_DIM + foff);
      a0 += bflo(v.x); a1 += bfhi(v.x);
      a2 += bflo(v.y); a3 += bfhi(v.y);
      a4 += bflo(v.z); a5 += bfhi(v.z);
      a6 += bflo(v.w); a7 += bfhi(v.w);
    }
  }
  a0 += __shfl_xor(a0, 16); a0 += __shfl_xor(a0, 32);
  a1 += __shfl_xor(a1, 16); a1 += __shfl_xor(a1, 32);
  a2 += __shfl_xor(a2, 16); a2 += __shfl_xor(a2, 32);
  a3 += __shfl_xor(a3, 16); a3 += __shfl_xor(a3, 32);
  a4 += __shfl_xor(a4, 16); a4 += __shfl_xor(a4, 32);
  a5 += __shfl_xor(a5, 16); a5 += __shfl_xor(a5, 32);
  a6 += __shfl_xor(a6, 16); a6 += __shfl_xor(a6, 32);
  a7 += __shfl_xor(a7, 16); a7 += __shfl_xor(a7, 32);
  if (g == 0 && act) {
    const float inv = inv_deg[n];
    uint4 o;
    o.x = (uint32_t)f2bf(a0 * inv) | ((uint32_t)f2bf(a1 * inv) << 16);
    o.y = (uint32_t)f2bf(a2 * inv) | ((uint32_t)f2bf(a3 * inv) << 16);
    o.z = (uint32_t)f2bf(a4 * inv) | ((uint32_t)f2bf(a5 * inv) << 16);
    o.w = (uint32_t)f2bf(a6 * inv) | ((uint32_t)f2bf(a7 * inv) << 16);
    *(uint4*)(AGGb + (size_t)n * IN_DIM + foff) = o;
  }
}

__global__ __launch_bounds__(256) void final_kernel(const uint16_t* __restrict__ T2b,
    const float* __restrict__ R2, const uint16_t* __restrict__ adj16,
    const int* __restrict__ rowptr, const float* __restrict__ inv_deg,
    float* __restrict__ out, int nNodes) {
  const int wave = threadIdx.x >> 6;
  const int lane = threadIdx.x & 63;
  const int n = blockIdx.x * 4 + wave;
  if (n >= nNodes) return;
  const int beg = rowptr[n], end = rowptr[n + 1];
  const int g = lane >> 4;
  const int j = lane & 15;
  const int foff = j * 4;
  float a0 = 0.f, a1 = 0.f, a2 = 0.f, a3 = 0.f;

  for (int bb = beg; bb < end; bb += 64) {
    const int cnt = min(64, end - bb);
    const int adjv = (lane < cnt) ? (int)adj16[bb + lane] : 0;
    const int qsteps = (cnt + 3) >> 2;
    int it = 0;
    for (; it + 4 <= qsteps; it += 4) {
      uint2 v[4];
#pragma unroll
      for (int u = 0; u < 4; ++u) {
        const int e = 4 * (it + u) + g;
        const int s = __shfl(adjv, e);
        v[u] = make_uint2(0u, 0u);
        if (e < cnt) v[u] = *(const uint2*)(T2b + (size_t)s * 64 + foff);
      }
      __builtin_amdgcn_sched_barrier(0);
#pragma unroll
      for (int u = 0; u < 4; ++u) {
        a0 += bflo(v[u].x); a1 += bfhi(v[u].x);
        a2 += bflo(v[u].y); a3 += bfhi(v[u].y);
      }
    }
    for (; it < qsteps; ++it) {
      const int e = 4 * it + g;
      const int s = __shfl(adjv, e);
      uint2 v = make_uint2(0u, 0u);
      if (e < cnt) v = *(const uint2*)(T2b + (size_t)s * 64 + foff);
      a0 += bflo(v.x); a1 += bfhi(v.x);
      a2 += bflo(v.y); a3 += bfhi(v.y);
    }
  }
  a0 += __shfl_xor(a0, 16); a0 += __shfl_xor(a0, 32);
  a1 += __shfl_xor(a1, 16); a1 += __shfl_xor(a1, 32);
  a2 += __shfl_xor(a2, 16); a2 += __shfl_xor(a2, 32);
  a3 += __shfl_xor(a3, 16); a3 += __shfl_xor(a3, 32);
  if (g == 0) {
    const float inv = inv_deg[n];
    const float4 r = *(const float4*)(R2 + (size_t)n * 64 + foff);
    float4 o;
    o.x = a0 * inv + r.x;
    o.y = a1 * inv + r.y;
    o.z = a2 * inv + r.z;
    o.w = a3 * inv + r.w;
    *(float4*)(out + (size_t)n * 64 + foff) = o;
  }
}

// ---------------- fused MFMA GEMM1+GEMM2, B staged in LDS ----------------
// Block = 4 waves = 64 rows; wave = 16 rows x 128 cols.
// Phase 1: B = S1t in LDS pitch 200 (bank-uniform for the frag pattern);
// phase 2: B = S2t re-staged over the same LDS, pitch 136; H in a separate
// wave-private LDS tile (pitch 136). A-frags preloaded into registers.
#define SP1 200
#define SP2 136
#define HP 136
__global__ __launch_bounds__(256) void gemm12_kernel(
    const uint16_t* __restrict__ AGGb, const uint16_t* __restrict__ xb,
    const uint16_t* __restrict__ S1t, const uint16_t* __restrict__ S2t,
    const float* __restrict__ b1, const float* __restrict__ b2,
    uint16_t* __restrict__ T2b, float* __restrict__ R2, int M) {
  __shared__ uint16_t BS[128 * SP1];   // 51.2KB; first 128*SP2 reused for S2t
  __shared__ uint16_t Hs[64 * HP];     // 17.4KB
  const int tid = threadIdx.x;
  const int wv = tid >> 6;
  const int lane = tid & 63;
  const int m16 = lane & 15;
  const int quad = lane >> 4;
  const int rowBase = blockIdx.x * 64 + wv * 16;
  int arow = rowBase + m16;
  if (arow >= M) arow = M - 1;  // clamp; stores guarded
  const int kq = quad * 8;

  // ---- stage S1t -> BS (pitch SP1), coalesced 16B chunks ----
#pragma unroll
  for (int i = 0; i < 12; ++i) {
    const int idx8 = tid + i * 256;          // 3072 chunks of 8 ushorts
    const int col = idx8 / 24;               // 24 chunks per 192-wide row
    const int k8 = (idx8 - col * 24) * 8;
    const bf16x8 v = *(const bf16x8*)(S1t + (size_t)idx8 * 8);
    *(bf16x8*)&BS[col * SP1 + k8] = v;
  }
  // ---- preload all 6 A-frags (independent global loads, one round-trip) ----
  bf16x8 a1f[6];
#pragma unroll
  for (int s = 0; s < 3; ++s)
    a1f[s] = *(const bf16x8*)(AGGb + (size_t)arow * IN_DIM + s * 32 + kq);
#pragma unroll
  for (int s = 0; s < 3; ++s)
    a1f[3 + s] = *(const bf16x8*)(xb + (size_t)arow * IN_DIM + s * 32 + kq);
  __syncthreads();

  // ---- GEMM1 k-loop: pure LDS + MFMA ----
  f32x4 acc1[8];
#pragma unroll
  for (int cf = 0; cf < 8; ++cf) acc1[cf] = (f32x4){0.f, 0.f, 0.f, 0.f};
#pragma unroll
  for (int s = 0; s < 6; ++s) {
#pragma unroll
    for (int cf = 0; cf < 8; ++cf) {
      const bf16x8 b = *(const bf16x8*)&BS[(cf * 16 + m16) * SP1 + s * 32 + kq];
      acc1[cf] = __builtin_amdgcn_mfma_f32_16x16x32_bf16(a1f[s], b, acc1[cf], 0, 0, 0);
    }
  }

  // epilogue1: relu(acc1 + b1) -> bf16 -> wave-private Hs rows
#pragma unroll
  for (int cf = 0; cf < 8; ++cf) {
    const int col = cf * 16 + m16;
    const float bias = b1[col];
#pragma unroll
    for (int r = 0; r < 4; ++r) {
      const float v = fmaxf(acc1[cf][r] + bias, 0.f);
      Hs[(wv * 16 + quad * 4 + r) * HP + col] = f2bf(v);
    }
  }
  __syncthreads();  // all waves done reading S1t region before overwrite

  // ---- stage S2t -> BS (pitch SP2) ----
#pragma unroll
  for (int i = 0; i < 8; ++i) {
    const int idx8 = tid + i * 256;          // 2048 chunks
    const int col = idx8 >> 4;               // 16 chunks per 128-wide row
    const int k8 = (idx8 & 15) * 8;
    const bf16x8 v = *(const bf16x8*)(S2t + (size_t)idx8 * 8);
    *(bf16x8*)&BS[col * SP2 + k8] = v;
  }
  __syncthreads();

  // ---- GEMM2 k-loop: A from Hs (own wave rows), B from BS ----
  f32x4 acc2[8];
#pragma unroll
  for (int cf = 0; cf < 8; ++cf) acc2[cf] = (f32x4){0.f, 0.f, 0.f, 0.f};
#pragma unroll
  for (int s = 0; s < 4; ++s) {
    const bf16x8 a = *(const bf16x8*)&Hs[(wv * 16 + m16) * HP + s * 32 + kq];
#pragma unroll
    for (int cf = 0; cf < 8; ++cf) {
      const bf16x8 b = *(const bf16x8*)&BS[(cf * 16 + m16) * SP2 + s * 32 + kq];
      acc2[cf] = __builtin_amdgcn_mfma_f32_16x16x32_bf16(a, b, acc2[cf], 0, 0, 0);
    }
  }

  // epilogue2: col<64 -> T2b bf16; col>=64 -> R2 f32 (+b2)
#pragma unroll
  for (int cf = 0; cf < 8; ++cf) {
    const int col = cf * 16 + m16;
#pragma unroll
    for (int r = 0; r < 4; ++r) {
      const int row = rowBase + quad * 4 + r;
      if (row < M) {
        const float v = acc2[cf][r];
        if (col < 64) {
          T2b[(size_t)row * 64 + col] = f2bf(v);
        } else {
          R2[(size_t)row * 64 + (col - 64)] = v + b2[col - 64];
        }
      }
    }
  }
}

extern "C" void kernel_launch(void* const* d_in, const int* in_sizes, int n_in,
                              void* d_out, int out_size, void* d_ws, size_t ws_size,
                              hipStream_t stream) {
  const float* x   = (const float*)d_in[0];
  const int*   ei  = (const int*)d_in[1];
  const float* w1l = (const float*)d_in[2];
  const float* b1  = (const float*)d_in[3];
  const float* w1r = (const float*)d_in[4];
  const float* w2l = (const float*)d_in[5];
  const float* b2  = (const float*)d_in[6];
  const float* w2r = (const float*)d_in[7];
  float* out = (float*)d_out;

  const int N = in_sizes[0] / IN_DIM;   // 50000
  const int E = in_sizes[1] / 2;        // 800000
  const int* src = ei;
  const int* dst = ei + E;
  const int NB = (N + 255) >> 8;        // 196 buckets

  // ---- workspace carve (AGGb DISJOINT from T2b/R2 — round-7 bug) ----
  char* p = (char*)d_ws;
  uint16_t* AGGb = (uint16_t*)p; p += alignUp((size_t)N * IN_DIM * sizeof(uint16_t), 256);
  uint16_t* T2b  = (uint16_t*)p; p += alignUp((size_t)N * 64 * sizeof(uint16_t), 256);
  float* R2      = (float*)p;    p += alignUp((size_t)N * 64 * sizeof(float), 256);
  uint16_t* xb = (uint16_t*)p; p += alignUp((size_t)N * IN_DIM * sizeof(uint16_t), 256);
  uint16_t* S1t = (uint16_t*)p; p += alignUp(NS1 * sizeof(uint16_t), 256);
  uint16_t* S2t = (uint16_t*)p; p += alignUp(NS2 * sizeof(uint16_t), 256);
  int* rowptr = (int*)p; p += alignUp((size_t)(N + 1) * sizeof(int), 256);
  float* inv_deg = (float*)p; p += alignUp((size_t)N * sizeof(float), 256);
  uint16_t* adj16 = (uint16_t*)p; p += alignUp((size_t)E * sizeof(uint16_t), 256);
  uint32_t* bucketBuf = (uint32_t*)p; p += alignUp((size_t)E * sizeof(uint32_t), 256);
  int* bucketCnt = (int*)p;    p += alignUp(256 * sizeof(int), 256);
  int* bucketBase = (int*)p;   p += alignUp(257 * sizeof(int), 256);
  int* bucketCursor = (int*)p; p += alignUp(256 * sizeof(int), 256);
  (void)ws_size; (void)n_in; (void)out_size;

  hipMemsetAsync(bucketCnt, 0, 256 * sizeof(int), stream);

  bucket_count_kernel<<<256, 256, 0, stream>>>(dst, bucketCnt, E);
  bucket_scan_kernel<<<1, 256, 0, stream>>>(bucketCnt, bucketBase, bucketCursor, rowptr, NB, N);
  bucket_scatter_kernel<<<(E + SCAT_CHUNK - 1) / SCAT_CHUNK, 256, 0, stream>>>(
      src, dst, bucketCursor, bucketBuf, E);
  bucket_build_kernel<<<NB, 256, 0, stream>>>(bucketBuf, bucketBase, rowptr, inv_deg, adj16, N);

  const int total4 = N * IN_DIM / 4;
  const int prepThreads = NS1 + NS2 + total4;
  prep_kernel<<<(prepThreads + 255) / 256, 256, 0, stream>>>(x, w1l, w1r, w2l, w2r,
                                                             S1t, S2t, xb, total4);

  const int nodeBlocks = (N + 3) / 4;
  agg1_kernel<<<nodeBlocks, 256, 0, stream>>>(xb, adj16, rowptr, inv_deg, AGGb, N);

  const int gemmBlocks = (N + 63) / 64;
  gemm12_kernel<<<gemmBlocks, 256, 0, stream>>>(AGGb, xb, S1t, S2t, b1, b2, T2b, R2, N);

  final_kernel<<<nodeBlocks, 256, 0, stream>>>(T2b, R2, adj16, rowptr, inv_deg, out, N);
}

// Round 11
// 187.886 us; speedup vs baseline: 2.8639x; 1.0014x over previous
//
#include <hip/hip_runtime.h>
#include <cstdint>
#include <cstddef>

// BinSAGE: 2-layer GraphSAGE with sign-binarized weights. MFMA bf16 + bucket-sort CSR.
// N=50000 nodes, E=800000 edges, dims 96 -> 128 -> 64.
//   CSR build: bucket counting sort (196 buckets of 256 nodes), adj stored u16.
//     count uses per-block partial histograms (no memset, no global atomics).
//   prep (1 dispatch): S1t/S2t sign matrices bf16 + xb = bf16(x)
//   agg1: mean of xb over in-edges -> AGGb bf16 [N,96]
//   gemm12 (fused MFMA, B staged in LDS): [AGGb|xb] @ S1t^T -> relu -> H (LDS)
//                                         H @ S2t^T -> T2b bf16 + R2 f32
//   final: out = inv_deg * segsum(T2b[src]) + R2
// Gather design (R11): wave = 4 nodes, 16-lane subgroup = 1 node. adj indices
// via same-address broadcast loads (no LDS shfl in the chain), 4 independent
// adj->gather chains per iteration, no cross-subgroup combine. inv_deg
// computed from rowptr delta (array removed).
// R9 lesson kept: GEMM B must be LDS-staged (per-wave-redundant global B reads
// serialize at ~1.2k cyc/load). R7 lesson kept: AGGb disjoint from T2b/R2.

#define N_NODES 50000
#define IN_DIM 96
#define HID 128
#define OUT_DIM 64

typedef __attribute__((ext_vector_type(8))) short bf16x8;
typedef __attribute__((ext_vector_type(4))) float f32x4;

static inline size_t alignUp(size_t v, size_t a) { return (v + a - 1) & ~(a - 1); }

__device__ __forceinline__ uint16_t f2bf(float f) {
  uint32_t u = __float_as_uint(f);
  return (uint16_t)((u + 0x7FFF + ((u >> 16) & 1)) >> 16);
}
__device__ __forceinline__ float bflo(uint32_t v) { return __uint_as_float(v << 16); }
__device__ __forceinline__ float bfhi(uint32_t v) { return __uint_as_float(v & 0xFFFF0000u); }

// ---------------- CSR build: bucketed counting sort ----------------
// Phase 1: 256 blocks, each writes a private 256-bucket histogram row.
__global__ __launch_bounds__(256) void bucket_count_kernel(const int* __restrict__ dst,
    int* __restrict__ bucketPart, int E) {
  __shared__ int h[256];
  const int t = threadIdx.x;
  h[t] = 0;
  __syncthreads();
  const int stride = gridDim.x * 256;
  for (int i = blockIdx.x * 256 + t; i < E; i += stride)
    atomicAdd(&h[dst[i] >> 8], 1);
  __syncthreads();
  bucketPart[blockIdx.x * 256 + t] = h[t];
}

// Phase 2 (1 block): column-sum partials -> counts, scan -> bases/cursors.
__global__ __launch_bounds__(256) void bucket_scan_kernel(const int* __restrict__ bucketPart,
    int* __restrict__ bucketBase, int* __restrict__ bucketCursor, int* __restrict__ rowptr,
    int nB, int N) {
  __shared__ int smem[256];
  const int t = threadIdx.x;
  int v = 0;
  for (int b = 0; b < 256; ++b) v += bucketPart[b * 256 + t];  // coalesced
  if (t >= nB) v = 0;
  smem[t] = v;
  __syncthreads();
  for (int off = 1; off < 256; off <<= 1) {
    int u = (t >= off) ? smem[t - off] : 0;
    __syncthreads();
    smem[t] += u;
    __syncthreads();
  }
  if (t < nB) {
    const int excl = smem[t] - v;
    bucketBase[t] = excl;
    bucketCursor[t] = excl;
  }
  if (t == 255) {
    bucketBase[nB] = smem[255];
    rowptr[N] = smem[255];
  }
}

#define SCAT_CHUNK 2048
__global__ __launch_bounds__(256) void bucket_scatter_kernel(const int* __restrict__ src,
    const int* __restrict__ dst, int* __restrict__ bucketCursor,
    uint32_t* __restrict__ bucketBuf, int E) {
  __shared__ int h[256];
  __shared__ int g[256];
  __shared__ int c[256];
  const int t = threadIdx.x;
  const int base = blockIdx.x * SCAT_CHUNK;
  const int end = min(base + SCAT_CHUNK, E);
  h[t] = 0;
  __syncthreads();
  for (int i = base + t; i < end; i += 256)
    atomicAdd(&h[dst[i] >> 8], 1);
  __syncthreads();
  if (h[t]) g[t] = atomicAdd(&bucketCursor[t], h[t]);
  c[t] = 0;
  __syncthreads();
  for (int i = base + t; i < end; i += 256) {
    const int d = dst[i];
    const int b = d >> 8;
    const int ticket = atomicAdd(&c[b], 1);
    bucketBuf[g[b] + ticket] = (uint32_t)src[i] | ((uint32_t)(d & 255) << 16);
  }
}

__global__ __launch_bounds__(256) void bucket_build_kernel(const uint32_t* __restrict__ bucketBuf,
    const int* __restrict__ bucketBase, int* __restrict__ rowptr,
    uint16_t* __restrict__ adj16, int N) {
  __shared__ int h[256];
  __shared__ int s[256];
  __shared__ int cur[256];
  const int t = threadIdx.x;
  const int b = blockIdx.x;
  const int nodeBase = b << 8;
  const int beg = bucketBase[b], end = bucketBase[b + 1];
  const int m = end - beg;
  h[t] = 0;
  __syncthreads();
  for (int i = t; i < m; i += 256)
    atomicAdd(&h[(bucketBuf[beg + i] >> 16) & 255], 1);
  __syncthreads();
  const int d = h[t];
  s[t] = d;
  __syncthreads();
  for (int off = 1; off < 256; off <<= 1) {
    int u = (t >= off) ? s[t - off] : 0;
    __syncthreads();
    s[t] += u;
    __syncthreads();
  }
  const int excl = s[t] - d;
  const int node = nodeBase + t;
  if (node < N) rowptr[node] = beg + excl;
  cur[t] = excl;
  __syncthreads();
  for (int i = t; i < m; i += 256) {
    const uint32_t u = bucketBuf[beg + i];
    const int ld = (u >> 16) & 255;
    const int ticket = atomicAdd(&cur[ld], 1);
    adj16[beg + ticket] = (uint16_t)(u & 0xFFFFu);
  }
}

// ---------------- combined prep: sign matrices + x->bf16 ----------------
__device__ __forceinline__ uint16_t sgnbf(float w) {
  return (w > 0.f) ? (uint16_t)0x3F80 : ((w < 0.f) ? (uint16_t)0xBF80 : (uint16_t)0);
}

#define NS1 (128 * 192)
#define NS2 (128 * 128)
__global__ __launch_bounds__(256) void prep_kernel(const float* __restrict__ x,
    const float* __restrict__ w1l, const float* __restrict__ w1r,
    const float* __restrict__ w2l, const float* __restrict__ w2r,
    uint16_t* __restrict__ S1t, uint16_t* __restrict__ S2t,
    uint16_t* __restrict__ xb, int total4) {
  int idx = blockIdx.x * blockDim.x + threadIdx.x;
  if (idx < NS1) {
    int n = idx / 192, k = idx - n * 192;
    float w = (k < 96) ? w1l[n * 96 + k] : w1r[n * 96 + (k - 96)];
    S1t[idx] = sgnbf(w);
  } else if (idx < NS1 + NS2) {
    int i2 = idx - NS1;
    int n = i2 >> 7, k = i2 & 127;
    float w = (n < 64) ? w2l[n * 128 + k] : w2r[(n - 64) * 128 + k];
    S2t[i2] = sgnbf(w);
  } else {
    int i = idx - NS1 - NS2;
    if (i < total4) {
      float4 v = *(const float4*)(x + (size_t)i * 4);
      uint32_t p0 = (uint32_t)f2bf(v.x) | ((uint32_t)f2bf(v.y) << 16);
      uint32_t p1 = (uint32_t)f2bf(v.z) | ((uint32_t)f2bf(v.w) << 16);
      *(uint2*)(xb + (size_t)i * 4) = make_uint2(p0, p1);
    }
  }
}

// ---------------- gathers: subgroup(16) = node ----------------
// agg1: lane j<12 covers features 8j..8j+7 (uint4); 4 edges per iter, adj via
// same-address broadcast u16 loads -> 4 independent adj->gather chains.
__global__ __launch_bounds__(256) void agg1_kernel(const uint16_t* __restrict__ xb,
    const uint16_t* __restrict__ adj16, const int* __restrict__ rowptr,
    uint16_t* __restrict__ AGGb, int nNodes) {
  const int sg = threadIdx.x >> 4;
  const int j = threadIdx.x & 15;
  const int n = blockIdx.x * 16 + sg;
  if (n >= nNodes) return;
  const int beg = rowptr[n], end = rowptr[n + 1];
  const bool act = j < 12;
  const int foff = j * 8;
  float a0 = 0.f, a1 = 0.f, a2 = 0.f, a3 = 0.f, a4 = 0.f, a5 = 0.f, a6 = 0.f, a7 = 0.f;

  int e = beg;
  for (; e + 4 <= end; e += 4) {
    const int s0 = adj16[e], s1 = adj16[e + 1], s2 = adj16[e + 2], s3 = adj16[e + 3];
    uint4 v0 = make_uint4(0u,0u,0u,0u), v1 = v0, v2 = v0, v3 = v0;
    if (act) {
      v0 = *(const uint4*)(xb + (size_t)s0 * IN_DIM + foff);
      v1 = *(const uint4*)(xb + (size_t)s1 * IN_DIM + foff);
      v2 = *(const uint4*)(xb + (size_t)s2 * IN_DIM + foff);
      v3 = *(const uint4*)(xb + (size_t)s3 * IN_DIM + foff);
    }
    __builtin_amdgcn_sched_barrier(0);
    a0 += bflo(v0.x) + bflo(v1.x) + bflo(v2.x) + bflo(v3.x);
    a1 += bfhi(v0.x) + bfhi(v1.x) + bfhi(v2.x) + bfhi(v3.x);
    a2 += bflo(v0.y) + bflo(v1.y) + bflo(v2.y) + bflo(v3.y);
    a3 += bfhi(v0.y) + bfhi(v1.y) + bfhi(v2.y) + bfhi(v3.y);
    a4 += bflo(v0.z) + bflo(v1.z) + bflo(v2.z) + bflo(v3.z);
    a5 += bfhi(v0.z) + bfhi(v1.z) + bfhi(v2.z) + bfhi(v3.z);
    a6 += bflo(v0.w) + bflo(v1.w) + bflo(v2.w) + bflo(v3.w);
    a7 += bfhi(v0.w) + bfhi(v1.w) + bfhi(v2.w) + bfhi(v3.w);
  }
  for (; e < end; ++e) {
    const int s = adj16[e];
    uint4 v = make_uint4(0u,0u,0u,0u);
    if (act) v = *(const uint4*)(xb + (size_t)s * IN_DIM + foff);
    a0 += bflo(v.x); a1 += bfhi(v.x);
    a2 += bflo(v.y); a3 += bfhi(v.y);
    a4 += bflo(v.z); a5 += bfhi(v.z);
    a6 += bflo(v.w); a7 += bfhi(v.w);
  }
  if (act) {
    const int d = end - beg;
    const float inv = 1.0f / (float)(d > 1 ? d : 1);
    uint4 o;
    o.x = (uint32_t)f2bf(a0 * inv) | ((uint32_t)f2bf(a1 * inv) << 16);
    o.y = (uint32_t)f2bf(a2 * inv) | ((uint32_t)f2bf(a3 * inv) << 16);
    o.z = (uint32_t)f2bf(a4 * inv) | ((uint32_t)f2bf(a5 * inv) << 16);
    o.w = (uint32_t)f2bf(a6 * inv) | ((uint32_t)f2bf(a7 * inv) << 16);
    *(uint4*)(AGGb + (size_t)n * IN_DIM + foff) = o;
  }
}

// final: subgroup(16) = node; lane j covers features 4j..4j+3 (uint2 of T2b).
__global__ __launch_bounds__(256) void final_kernel(const uint16_t* __restrict__ T2b,
    const float* __restrict__ R2, const uint16_t* __restrict__ adj16,
    const int* __restrict__ rowptr, float* __restrict__ out, int nNodes) {
  const int sg = threadIdx.x >> 4;
  const int j = threadIdx.x & 15;
  const int n = blockIdx.x * 16 + sg;
  if (n >= nNodes) return;
  const int beg = rowptr[n], end = rowptr[n + 1];
  const int foff = j * 4;
  float a0 = 0.f, a1 = 0.f, a2 = 0.f, a3 = 0.f;

  int e = beg;
  for (; e + 4 <= end; e += 4) {
    const int s0 = adj16[e], s1 = adj16[e + 1], s2 = adj16[e + 2], s3 = adj16[e + 3];
    const uint2 v0 = *(const uint2*)(T2b + (size_t)s0 * 64 + foff);
    const uint2 v1 = *(const uint2*)(T2b + (size_t)s1 * 64 + foff);
    const uint2 v2 = *(const uint2*)(T2b + (size_t)s2 * 64 + foff);
    const uint2 v3 = *(const uint2*)(T2b + (size_t)s3 * 64 + foff);
    __builtin_amdgcn_sched_barrier(0);
    a0 += bflo(v0.x) + bflo(v1.x) + bflo(v2.x) + bflo(v3.x);
    a1 += bfhi(v0.x) + bfhi(v1.x) + bfhi(v2.x) + bfhi(v3.x);
    a2 += bflo(v0.y) + bflo(v1.y) + bflo(v2.y) + bflo(v3.y);
    a3 += bfhi(v0.y) + bfhi(v1.y) + bfhi(v2.y) + bfhi(v3.y);
  }
  for (; e < end; ++e) {
    const int s = adj16[e];
    const uint2 v = *(const uint2*)(T2b + (size_t)s * 64 + foff);
    a0 += bflo(v.x); a1 += bfhi(v.x);
    a2 += bflo(v.y); a3 += bfhi(v.y);
  }
  const int d = end - beg;
  const float inv = 1.0f / (float)(d > 1 ? d : 1);
  const float4 r = *(const float4*)(R2 + (size_t)n * 64 + foff);
  float4 o;
  o.x = a0 * inv + r.x;
  o.y = a1 * inv + r.y;
  o.z = a2 * inv + r.z;
  o.w = a3 * inv + r.w;
  *(float4*)(out + (size_t)n * 64 + foff) = o;
}

// ---------------- fused MFMA GEMM1+GEMM2, B staged in LDS (R10) ----------------
#define SP1 200
#define SP2 136
#define HP 136
__global__ __launch_bounds__(256) void gemm12_kernel(
    const uint16_t* __restrict__ AGGb, const uint16_t* __restrict__ xb,
    const uint16_t* __restrict__ S1t, const uint16_t* __restrict__ S2t,
    const float* __restrict__ b1, const float* __restrict__ b2,
    uint16_t* __restrict__ T2b, float* __restrict__ R2, int M) {
  __shared__ uint16_t BS[128 * SP1];
  __shared__ uint16_t Hs[64 * HP];
  const int tid = threadIdx.x;
  const int wv = tid >> 6;
  const int lane = tid & 63;
  const int m16 = lane & 15;
  const int quad = lane >> 4;
  const int rowBase = blockIdx.x * 64 + wv * 16;
  int arow = rowBase + m16;
  if (arow >= M) arow = M - 1;
  const int kq = quad * 8;

#pragma unroll
  for (int i = 0; i < 12; ++i) {
    const int idx8 = tid + i * 256;
    const int col = idx8 / 24;
    const int k8 = (idx8 - col * 24) * 8;
    const bf16x8 v = *(const bf16x8*)(S1t + (size_t)idx8 * 8);
    *(bf16x8*)&BS[col * SP1 + k8] = v;
  }
  bf16x8 a1f[6];
#pragma unroll
  for (int s = 0; s < 3; ++s)
    a1f[s] = *(const bf16x8*)(AGGb + (size_t)arow * IN_DIM + s * 32 + kq);
#pragma unroll
  for (int s = 0; s < 3; ++s)
    a1f[3 + s] = *(const bf16x8*)(xb + (size_t)arow * IN_DIM + s * 32 + kq);
  __syncthreads();

  f32x4 acc1[8];
#pragma unroll
  for (int cf = 0; cf < 8; ++cf) acc1[cf] = (f32x4){0.f, 0.f, 0.f, 0.f};
#pragma unroll
  for (int s = 0; s < 6; ++s) {
#pragma unroll
    for (int cf = 0; cf < 8; ++cf) {
      const bf16x8 b = *(const bf16x8*)&BS[(cf * 16 + m16) * SP1 + s * 32 + kq];
      acc1[cf] = __builtin_amdgcn_mfma_f32_16x16x32_bf16(a1f[s], b, acc1[cf], 0, 0, 0);
    }
  }

#pragma unroll
  for (int cf = 0; cf < 8; ++cf) {
    const int col = cf * 16 + m16;
    const float bias = b1[col];
#pragma unroll
    for (int r = 0; r < 4; ++r) {
      const float v = fmaxf(acc1[cf][r] + bias, 0.f);
      Hs[(wv * 16 + quad * 4 + r) * HP + col] = f2bf(v);
    }
  }
  __syncthreads();

#pragma unroll
  for (int i = 0; i < 8; ++i) {
    const int idx8 = tid + i * 256;
    const int col = idx8 >> 4;
    const int k8 = (idx8 & 15) * 8;
    const bf16x8 v = *(const bf16x8*)(S2t + (size_t)idx8 * 8);
    *(bf16x8*)&BS[col * SP2 + k8] = v;
  }
  __syncthreads();

  f32x4 acc2[8];
#pragma unroll
  for (int cf = 0; cf < 8; ++cf) acc2[cf] = (f32x4){0.f, 0.f, 0.f, 0.f};
#pragma unroll
  for (int s = 0; s < 4; ++s) {
    const bf16x8 a = *(const bf16x8*)&Hs[(wv * 16 + m16) * HP + s * 32 + kq];
#pragma unroll
    for (int cf = 0; cf < 8; ++cf) {
      const bf16x8 b = *(const bf16x8*)&BS[(cf * 16 + m16) * SP2 + s * 32 + kq];
      acc2[cf] = __builtin_amdgcn_mfma_f32_16x16x32_bf16(a, b, acc2[cf], 0, 0, 0);
    }
  }

#pragma unroll
  for (int cf = 0; cf < 8; ++cf) {
    const int col = cf * 16 + m16;
#pragma unroll
    for (int r = 0; r < 4; ++r) {
      const int row = rowBase + quad * 4 + r;
      if (row < M) {
        const float v = acc2[cf][r];
        if (col < 64) {
          T2b[(size_t)row * 64 + col] = f2bf(v);
        } else {
          R2[(size_t)row * 64 + (col - 64)] = v + b2[col - 64];
        }
      }
    }
  }
}

extern "C" void kernel_launch(void* const* d_in, const int* in_sizes, int n_in,
                              void* d_out, int out_size, void* d_ws, size_t ws_size,
                              hipStream_t stream) {
  const float* x   = (const float*)d_in[0];
  const int*   ei  = (const int*)d_in[1];
  const float* w1l = (const float*)d_in[2];
  const float* b1  = (const float*)d_in[3];
  const float* w1r = (const float*)d_in[4];
  const float* w2l = (const float*)d_in[5];
  const float* b2  = (const float*)d_in[6];
  const float* w2r = (const float*)d_in[7];
  float* out = (float*)d_out;

  const int N = in_sizes[0] / IN_DIM;   // 50000
  const int E = in_sizes[1] / 2;        // 800000
  const int* src = ei;
  const int* dst = ei + E;
  const int NB = (N + 255) >> 8;        // 196 buckets

  // ---- workspace carve (AGGb DISJOINT from T2b/R2 — round-7 bug) ----
  char* p = (char*)d_ws;
  uint16_t* AGGb = (uint16_t*)p; p += alignUp((size_t)N * IN_DIM * sizeof(uint16_t), 256);
  uint16_t* T2b  = (uint16_t*)p; p += alignUp((size_t)N * 64 * sizeof(uint16_t), 256);
  float* R2      = (float*)p;    p += alignUp((size_t)N * 64 * sizeof(float), 256);
  uint16_t* xb = (uint16_t*)p; p += alignUp((size_t)N * IN_DIM * sizeof(uint16_t), 256);
  uint16_t* S1t = (uint16_t*)p; p += alignUp(NS1 * sizeof(uint16_t), 256);
  uint16_t* S2t = (uint16_t*)p; p += alignUp(NS2 * sizeof(uint16_t), 256);
  int* rowptr = (int*)p; p += alignUp((size_t)(N + 1) * sizeof(int), 256);
  uint16_t* adj16 = (uint16_t*)p; p += alignUp((size_t)E * sizeof(uint16_t), 256);
  uint32_t* bucketBuf = (uint32_t*)p; p += alignUp((size_t)E * sizeof(uint32_t), 256);
  int* bucketPart = (int*)p;   p += alignUp(256 * 256 * sizeof(int), 256);
  int* bucketBase = (int*)p;   p += alignUp(257 * sizeof(int), 256);
  int* bucketCursor = (int*)p; p += alignUp(256 * sizeof(int), 256);
  (void)ws_size; (void)n_in; (void)out_size;

  bucket_count_kernel<<<256, 256, 0, stream>>>(dst, bucketPart, E);
  bucket_scan_kernel<<<1, 256, 0, stream>>>(bucketPart, bucketBase, bucketCursor, rowptr, NB, N);
  bucket_scatter_kernel<<<(E + SCAT_CHUNK - 1) / SCAT_CHUNK, 256, 0, stream>>>(
      src, dst, bucketCursor, bucketBuf, E);
  bucket_build_kernel<<<NB, 256, 0, stream>>>(bucketBuf, bucketBase, rowptr, adj16, N);

  const int total4 = N * IN_DIM / 4;
  const int prepThreads = NS1 + NS2 + total4;
  prep_kernel<<<(prepThreads + 255) / 256, 256, 0, stream>>>(x, w1l, w1r, w2l, w2r,
                                                             S1t, S2t, xb, total4);

  const int nodeBlocks16 = (N + 15) / 16;
  agg1_kernel<<<nodeBlocks16, 256, 0, stream>>>(xb, adj16, rowptr, AGGb, N);

  const int gemmBlocks = (N + 63) / 64;
  gemm12_kernel<<<gemmBlocks, 256, 0, stream>>>(AGGb, xb, S1t, S2t, b1, b2, T2b, R2, N);

  final_kernel<<<nodeBlocks16, 256, 0, stream>>>(T2b, R2, adj16, rowptr, out, N);
}